// Round 1
// baseline (2132.867 us; speedup 1.0000x reference)
//
#include <hip/hip_runtime.h>

constexpr int NN = 50000;    // nodes
constexpr int NE = 800000;   // edges
constexpr int IND = 128;     // in dim
constexpr int HD = 256;      // hidden
constexpr int BS = 8192;     // seeds

// ---------------- flag needed nodes ----------------
__global__ __launch_bounds__(256) void k_flag(const int* __restrict__ ids,
                                              int* __restrict__ flag) {
  int i = blockIdx.x * 256 + threadIdx.x;
  if (i < BS) flag[ids[i]] = 1;
}

// ---------------- in-degree count ----------------
__global__ __launch_bounds__(256) void k_count(const int* __restrict__ dst,
                                               float* __restrict__ cnt) {
  int i = blockIdx.x * 256 + threadIdx.x;
  if (i < NE) atomicAdd(&cnt[dst[i]], 1.0f);
}

// ---------------- edge scatter-add (push, atomics) ----------------
template <int LOG2D, bool FLAGGED>
__global__ __launch_bounds__(256) void k_scatter(const int* __restrict__ src,
                                                 const int* __restrict__ dst,
                                                 const float* __restrict__ h,
                                                 float* __restrict__ agg,
                                                 const int* __restrict__ flag) {
  const int D = 1 << LOG2D;
  const long long total = (long long)NE << LOG2D;
  const long long stride = (long long)gridDim.x * 256;
  for (long long idx = (long long)blockIdx.x * 256 + threadIdx.x; idx < total;
       idx += stride) {
    int e = (int)(idx >> LOG2D);
    int d = (int)(idx & (D - 1));
    int dn = dst[e];
    if (FLAGGED && !flag[dn]) continue;
    atomicAdd(&agg[dn * D + d], h[src[e] * D + d]);
  }
}

// ---------------- scale rows by 1/max(cnt,1) ----------------
template <int LOG2D>
__global__ __launch_bounds__(256) void k_scale(float* __restrict__ agg,
                                               const float* __restrict__ cnt) {
  const int total = NN << LOG2D;
  for (int idx = blockIdx.x * 256 + threadIdx.x; idx < total;
       idx += gridDim.x * 256) {
    agg[idx] /= fmaxf(cnt[idx >> LOG2D], 1.0f);
  }
}

// ---------------- layer-1 GEMM: h1 = relu(neigh@Wn + x@Ws + b) ----------------
// BM=64, BN=64, BK=32, 256 threads, each 4x4
__global__ __launch_bounds__(256) void k_gemm1(const float* __restrict__ neigh,
                                               const float* __restrict__ xs,
                                               const float* __restrict__ Wn,
                                               const float* __restrict__ Ws,
                                               const float* __restrict__ bias,
                                               float* __restrict__ C) {
  __shared__ __align__(16) float An[32][68];
  __shared__ __align__(16) float As[32][68];
  __shared__ __align__(16) float Bn[32][68];
  __shared__ __align__(16) float Bs[32][68];
  const int t = threadIdx.x;
  const int tx = t & 15, ty = t >> 4;
  const int row0 = blockIdx.x * 64, col0 = blockIdx.y * 64;
  float acc[4][4] = {};
  for (int kk = 0; kk < IND; kk += 32) {
#pragma unroll
    for (int p = 0; p < 8; ++p) {
      int flat = p * 256 + t;
      int k = flat & 31, m = flat >> 5;
      int row = row0 + m;
      float va = 0.f, vs = 0.f;
      if (row < NN) {
        va = neigh[row * IND + kk + k];
        vs = xs[row * IND + kk + k];
      }
      An[k][m] = va;
      As[k][m] = vs;
    }
#pragma unroll
    for (int p = 0; p < 8; ++p) {
      int flat = p * 256 + t;
      int c = flat & 63, k = flat >> 6;
      Bn[k][c] = Wn[(kk + k) * HD + col0 + c];
      Bs[k][c] = Ws[(kk + k) * HD + col0 + c];
    }
    __syncthreads();
#pragma unroll
    for (int k = 0; k < 32; ++k) {
      float4 a1 = *(const float4*)&An[k][ty * 4];
      float4 a2 = *(const float4*)&As[k][ty * 4];
      float4 w1 = *(const float4*)&Bn[k][tx * 4];
      float4 w2 = *(const float4*)&Bs[k][tx * 4];
      float a1v[4] = {a1.x, a1.y, a1.z, a1.w};
      float a2v[4] = {a2.x, a2.y, a2.z, a2.w};
      float w1v[4] = {w1.x, w1.y, w1.z, w1.w};
      float w2v[4] = {w2.x, w2.y, w2.z, w2.w};
#pragma unroll
      for (int i = 0; i < 4; ++i)
#pragma unroll
        for (int j = 0; j < 4; ++j)
          acc[i][j] += a1v[i] * w1v[j] + a2v[i] * w2v[j];
    }
    __syncthreads();
  }
#pragma unroll
  for (int i = 0; i < 4; ++i) {
    int row = row0 + ty * 4 + i;
    if (row < NN) {
      int col = col0 + tx * 4;
      float4 v;
      v.x = fmaxf(acc[i][0] + bias[col + 0], 0.f);
      v.y = fmaxf(acc[i][1] + bias[col + 1], 0.f);
      v.z = fmaxf(acc[i][2] + bias[col + 2], 0.f);
      v.w = fmaxf(acc[i][3] + bias[col + 3], 0.f);
      *(float4*)&C[row * HD + col] = v;
    }
  }
}

// ---------------- layer-2 @ seeds + l2norm + head ----------------
// one block handles 8 seeds; 256 threads
template <bool FIRST>
__global__ __launch_bounds__(256) void k_layer2_out(
    const float* __restrict__ agg2, const float* __restrict__ cnt,
    const float* __restrict__ h1, const int* __restrict__ ids,
    const float* __restrict__ Wn2, const float* __restrict__ Ws2,
    const float* __restrict__ b2, const float* __restrict__ W_out,
    const float* __restrict__ b_out, float* __restrict__ out, int wout_off) {
  __shared__ __align__(16) float nT[8][HD];
  __shared__ __align__(16) float sT[8][HD];
  const int t = threadIdx.x;
  const int b0 = blockIdx.x * 8;
#pragma unroll
  for (int r = 0; r < 8; ++r) {
    int node = ids[b0 + r];
    float c = fmaxf(cnt[node], 1.0f);
    nT[r][t] = agg2[node * HD + t] / c;
    sT[r][t] = h1[node * HD + t];
  }
  __syncthreads();
  float acc[8] = {};
  for (int k4 = 0; k4 < HD; k4 += 4) {
    float wn[4], ws[4];
#pragma unroll
    for (int q = 0; q < 4; ++q) {
      wn[q] = Wn2[(k4 + q) * HD + t];
      ws[q] = Ws2[(k4 + q) * HD + t];
    }
#pragma unroll
    for (int r = 0; r < 8; ++r) {
      float4 nv = *(const float4*)&nT[r][k4];
      float4 sv = *(const float4*)&sT[r][k4];
      acc[r] += nv.x * wn[0] + nv.y * wn[1] + nv.z * wn[2] + nv.w * wn[3] +
                sv.x * ws[0] + sv.y * ws[1] + sv.z * ws[2] + sv.w * ws[3];
    }
  }
  __syncthreads();
#pragma unroll
  for (int r = 0; r < 8; ++r) nT[r][t] = acc[r] + b2[t];
  __syncthreads();
  const int wave = t >> 6, lane = t & 63;
#pragma unroll
  for (int rr = 0; rr < 2; ++rr) {
    int r = wave * 2 + rr;
    float ss = 0.f, dp = 0.f;
#pragma unroll
    for (int q = 0; q < 4; ++q) {
      float v = nT[r][lane * 4 + q];
      ss += v * v;
      dp += v * W_out[wout_off + lane * 4 + q];
    }
    for (int off = 32; off; off >>= 1) {
      ss += __shfl_down(ss, off);
      dp += __shfl_down(dp, off);
    }
    if (lane == 0) {
      float norm = sqrtf(ss);
      float val = dp / fmaxf(norm, 1e-12f);
      int b = b0 + r;
      if (FIRST)
        out[b] = val + b_out[0];
      else
        out[b] += val;
    }
  }
}

extern "C" void kernel_launch(void* const* d_in, const int* in_sizes, int n_in,
                              void* d_out, int out_size, void* d_ws,
                              size_t ws_size, hipStream_t stream) {
  (void)in_sizes; (void)n_in; (void)out_size; (void)ws_size;
  const float* x_i = (const float*)d_in[0];
  const float* x_j = (const float*)d_in[1];
  const int* src_i = (const int*)d_in[2];
  const int* dst_i = (const int*)d_in[3];
  const int* src_j = (const int*)d_in[4];
  const int* dst_j = (const int*)d_in[5];
  const int* ids_i = (const int*)d_in[6];
  const int* ids_j = (const int*)d_in[7];
  const float* Wn1 = (const float*)d_in[8];
  const float* Ws1 = (const float*)d_in[9];
  const float* b1 = (const float*)d_in[10];
  const float* Wn2 = (const float*)d_in[11];
  const float* Ws2 = (const float*)d_in[12];
  const float* b2 = (const float*)d_in[13];
  const float* W_out = (const float*)d_in[14];
  const float* b_out = (const float*)d_in[15];
  float* out = (float*)d_out;

  char* w = (char*)d_ws;
  float* agg1 = (float*)(w);                 // 50000*128 f32 = 25,600,000 B
  float* h1   = (float*)(w + 25600000);      // 50000*256 f32 = 51,200,000 B
  float* agg2 = (float*)(w + 76800000);      // 50000*256 f32 = 51,200,000 B
  float* cnt  = (float*)(w + 128000000);     // 50000 f32     = 200,000 B
  int*   flag = (int*)  (w + 128200000);     // 50000 i32     = 200,000 B

  for (int g = 0; g < 2; ++g) {
    const float* x = g ? x_j : x_i;
    const int* src = g ? src_j : src_i;
    const int* dst = g ? dst_j : dst_i;
    const int* ids = g ? ids_j : ids_i;

    hipMemsetAsync(agg1, 0, 25600000, stream);
    hipMemsetAsync(agg2, 0, 51200000, stream);
    hipMemsetAsync(cnt, 0, 200000, stream);
    hipMemsetAsync(flag, 0, 200000, stream);

    k_flag<<<(BS + 255) / 256, 256, 0, stream>>>(ids, flag);
    k_count<<<(NE + 255) / 256, 256, 0, stream>>>(dst, cnt);
    k_scatter<7, false><<<4096, 256, 0, stream>>>(src, dst, x, agg1, nullptr);
    k_scale<7><<<2048, 256, 0, stream>>>(agg1, cnt);
    k_gemm1<<<dim3((NN + 63) / 64, HD / 64), 256, 0, stream>>>(agg1, x, Wn1,
                                                               Ws1, b1, h1);
    k_scatter<8, true><<<4096, 256, 0, stream>>>(src, dst, h1, agg2, flag);
    if (g == 0)
      k_layer2_out<true><<<BS / 8, 256, 0, stream>>>(
          agg2, cnt, h1, ids, Wn2, Ws2, b2, W_out, b_out, out, 0);
    else
      k_layer2_out<false><<<BS / 8, 256, 0, stream>>>(
          agg2, cnt, h1, ids, Wn2, Ws2, b2, W_out, b_out, out, HD);
  }
}

// Round 2
// 713.717 us; speedup vs baseline: 2.9884x; 2.9884x over previous
//
#include <hip/hip_runtime.h>

constexpr int NN = 50000;    // nodes
constexpr int NE = 800000;   // edges
constexpr int IND = 128;     // in dim
constexpr int HD = 256;      // hidden
constexpr int BS = 8192;     // seeds

typedef __attribute__((ext_vector_type(8))) short short8v;
typedef __attribute__((ext_vector_type(4))) float floatx4;

__device__ inline ushort f2b(float f) {  // f32 -> bf16 RNE
  unsigned u = __float_as_uint(f);
  unsigned r = (u + 0x7fffu + ((u >> 16) & 1u)) >> 16;
  return (ushort)r;
}

// ---------------- in-degree count (int) ----------------
__global__ __launch_bounds__(256) void k_count(const int* __restrict__ dst,
                                               int* __restrict__ cnt) {
  int i = blockIdx.x * 256 + threadIdx.x;
  if (i < NE) atomicAdd(&cnt[dst[i]], 1);
}

// ---------------- scan: exclusive within 256-block ----------------
__global__ __launch_bounds__(256) void k_scanA(const int* __restrict__ cnt,
                                               int* __restrict__ row_start,
                                               int* __restrict__ bsum) {
  __shared__ int s[256];
  int t = threadIdx.x;
  int i = blockIdx.x * 256 + t;
  s[t] = (i < NN) ? cnt[i] : 0;
  __syncthreads();
  if (t == 0) {
    int run = 0;
    for (int j = 0; j < 256; ++j) { int v = s[j]; s[j] = run; run += v; }
    bsum[blockIdx.x] = run;
  }
  __syncthreads();
  if (i < NN) row_start[i] = s[t];
}

__global__ __launch_bounds__(64) void k_scanB(int* __restrict__ bsum, int nb) {
  if (threadIdx.x == 0) {
    int run = 0;
    for (int j = 0; j < nb; ++j) { int v = bsum[j]; bsum[j] = run; run += v; }
  }
}

__global__ __launch_bounds__(256) void k_scanC(int* __restrict__ row_start,
                                               const int* __restrict__ bsum,
                                               int* __restrict__ cursor) {
  int i = blockIdx.x * 256 + threadIdx.x;
  if (i < NN) {
    int v = row_start[i] + bsum[i >> 8];
    row_start[i] = v;
    cursor[i] = v;
  }
}

// ---------------- fill CSR (bump-allocate) ----------------
__global__ __launch_bounds__(256) void k_fill(const int* __restrict__ src,
                                              const int* __restrict__ dst,
                                              int* __restrict__ cursor,
                                              int* __restrict__ csr_src) {
  int i = blockIdx.x * 256 + threadIdx.x;
  if (i < NE) {
    int pos = atomicAdd(&cursor[dst[i]], 1);
    csr_src[pos] = src[i];
  }
}

// ---------------- f32 -> bf16 convert ----------------
__global__ __launch_bounds__(256) void k_tobf16(const float* __restrict__ x,
                                                ushort* __restrict__ o, int n4) {
  int i = blockIdx.x * 256 + threadIdx.x;
  if (i < n4) {
    float4 v = *(const float4*)(x + i * 4);
    ushort4 u;
    u.x = f2b(v.x); u.y = f2b(v.y); u.z = f2b(v.z); u.w = f2b(v.w);
    *(ushort4*)(o + i * 4) = u;
  }
}

// ---------------- transpose+pack weights: Wt[n][k] bf16, k<128->Wn1 ----------------
__global__ __launch_bounds__(256) void k_wt(const float* __restrict__ Wn1,
                                            const float* __restrict__ Ws1,
                                            ushort* __restrict__ Wt) {
  int i = blockIdx.x * 256 + threadIdx.x;  // 65536
  int n = i >> 8, k = i & 255;
  float v = (k < 128) ? Wn1[k * HD + n] : Ws1[(k - 128) * HD + n];
  Wt[n * 256 + k] = f2b(v);
}

// ---------------- layer-1 pull aggregation: mean over in-neighbors ----------------
__global__ __launch_bounds__(256) void k_agg1(const float* __restrict__ x,
                                              const int* __restrict__ csr_src,
                                              const int* __restrict__ row_start,
                                              const int* __restrict__ cnt,
                                              ushort* __restrict__ aggb) {
  int w = threadIdx.x >> 6, l = threadIdx.x & 63;
  int node = blockIdx.x * 4 + w;
  if (node >= NN) return;
  int st = row_start[node], deg = cnt[node];
  float a0 = 0.f, a1 = 0.f;
  for (int e = 0; e < deg; ++e) {
    int s = csr_src[st + e];
    float2 v = *(const float2*)(x + s * IND + 2 * l);
    a0 += v.x; a1 += v.y;
  }
  float inv = 1.f / (float)max(deg, 1);
  ushort2 u;
  u.x = f2b(a0 * inv); u.y = f2b(a1 * inv);
  *(ushort2*)(aggb + node * IND + 2 * l) = u;
}

// ---------------- layer-1 MFMA GEMM: h1 = relu([agg|x] @ [Wn1;Ws1] + b1) ----------
// M=50000 N=256 K=256, tile 128x128, BK=32, 4 waves (2x2), 16x16x32 bf16
__global__ __launch_bounds__(256) void k_gemm1(const ushort* __restrict__ aggb,
                                               const ushort* __restrict__ xb,
                                               const ushort* __restrict__ Wt,
                                               const float* __restrict__ b1,
                                               float* __restrict__ h1) {
  __shared__ ushort Al[128 * 32];
  __shared__ ushort Bl[128 * 32];
  const int t = threadIdx.x;
  const int row0 = blockIdx.x * 128, col0 = blockIdx.y * 128;
  const int w = t >> 6, l = t & 63;
  const int wm = w & 1, wn = w >> 1;
  floatx4 acc[4][4];
#pragma unroll
  for (int i = 0; i < 4; ++i)
#pragma unroll
    for (int j = 0; j < 4; ++j) acc[i][j] = (floatx4){0.f, 0.f, 0.f, 0.f};

  for (int kk = 0; kk < 256; kk += 32) {
    const ushort* Abase = (kk < 128) ? (aggb + kk) : (xb + (kk - 128));
#pragma unroll
    for (int s = t; s < 512; s += 256) {  // stage A: 128 rows x 4 chunks
      int r = s >> 2, c = s & 3;
      int grow = row0 + r;
      short8v v = {0, 0, 0, 0, 0, 0, 0, 0};
      if (grow < NN) v = *(const short8v*)(Abase + grow * IND + c * 8);
      *(short8v*)(Al + r * 32 + ((c ^ (r & 3)) * 8)) = v;
    }
#pragma unroll
    for (int s = t; s < 512; s += 256) {  // stage B (Wt is [n][k] row-major)
      int r = s >> 2, c = s & 3;
      short8v v = *(const short8v*)(Wt + (col0 + r) * 256 + kk + c * 8);
      *(short8v*)(Bl + r * 32 + ((c ^ (r & 3)) * 8)) = v;
    }
    __syncthreads();
    const int rA = l & 15, g = l >> 4;
    short8v af[4], bf[4];
#pragma unroll
    for (int i = 0; i < 4; ++i) {
      int r = wm * 64 + i * 16 + rA;
      af[i] = *(const short8v*)(Al + r * 32 + ((g ^ (r & 3)) * 8));
    }
#pragma unroll
    for (int j = 0; j < 4; ++j) {
      int r = wn * 64 + j * 16 + rA;
      bf[j] = *(const short8v*)(Bl + r * 32 + ((g ^ (r & 3)) * 8));
    }
#pragma unroll
    for (int i = 0; i < 4; ++i)
#pragma unroll
      for (int j = 0; j < 4; ++j)
        acc[i][j] = __builtin_amdgcn_mfma_f32_16x16x32_bf16(af[i], bf[j],
                                                            acc[i][j], 0, 0, 0);
    __syncthreads();
  }
  // epilogue: D row=(l>>4)*4+r, col=l&15 within each 16x16 frag
  const int rD = l >> 4, cD = l & 15;
#pragma unroll
  for (int j = 0; j < 4; ++j) {
    int col = col0 + wn * 64 + j * 16 + cD;
    float bias = b1[col];
#pragma unroll
    for (int i = 0; i < 4; ++i) {
      int rbase = row0 + wm * 64 + i * 16 + rD * 4;
#pragma unroll
      for (int rr = 0; rr < 4; ++rr) {
        int row = rbase + rr;
        if (row < NN) h1[row * HD + col] = fmaxf(acc[i][j][rr] + bias, 0.f);
      }
    }
  }
}

// ---------------- layer-2 @ seeds (pull agg fused) + l2norm + head ----------------
template <bool FIRST>
__global__ __launch_bounds__(256) void k_layer2_out(
    const float* __restrict__ h1, const int* __restrict__ csr_src,
    const int* __restrict__ row_start, const int* __restrict__ cnt,
    const int* __restrict__ ids, const float* __restrict__ Wn2,
    const float* __restrict__ Ws2, const float* __restrict__ b2,
    const float* __restrict__ W_out, const float* __restrict__ b_out,
    float* __restrict__ out, int wout_off) {
  __shared__ __align__(16) float nT[8][HD];
  __shared__ __align__(16) float sT[8][HD];
  const int t = threadIdx.x;
  const int b0 = blockIdx.x * 8;
#pragma unroll
  for (int r = 0; r < 8; ++r) {
    int node = ids[b0 + r];
    int st = row_start[node], deg = cnt[node];
    float acc = 0.f;
    for (int e = 0; e < deg; ++e) {
      int s = csr_src[st + e];
      acc += h1[s * HD + t];
    }
    nT[r][t] = acc / (float)max(deg, 1);
    sT[r][t] = h1[node * HD + t];
  }
  __syncthreads();
  float acc[8] = {};
  for (int k4 = 0; k4 < HD; k4 += 4) {
    float wn[4], ws[4];
#pragma unroll
    for (int q = 0; q < 4; ++q) {
      wn[q] = Wn2[(k4 + q) * HD + t];
      ws[q] = Ws2[(k4 + q) * HD + t];
    }
#pragma unroll
    for (int r = 0; r < 8; ++r) {
      float4 nv = *(const float4*)&nT[r][k4];
      float4 sv = *(const float4*)&sT[r][k4];
      acc[r] += nv.x * wn[0] + nv.y * wn[1] + nv.z * wn[2] + nv.w * wn[3] +
                sv.x * ws[0] + sv.y * ws[1] + sv.z * ws[2] + sv.w * ws[3];
    }
  }
  __syncthreads();
#pragma unroll
  for (int r = 0; r < 8; ++r) nT[r][t] = acc[r] + b2[t];
  __syncthreads();
  const int wave = t >> 6, lane = t & 63;
#pragma unroll
  for (int rr = 0; rr < 2; ++rr) {
    int r = wave * 2 + rr;
    float ss = 0.f, dp = 0.f;
#pragma unroll
    for (int q = 0; q < 4; ++q) {
      float v = nT[r][lane * 4 + q];
      ss += v * v;
      dp += v * W_out[wout_off + lane * 4 + q];
    }
    for (int off = 32; off; off >>= 1) {
      ss += __shfl_down(ss, off);
      dp += __shfl_down(dp, off);
    }
    if (lane == 0) {
      float norm = sqrtf(ss);
      float val = dp / fmaxf(norm, 1e-12f);
      int b = b0 + r;
      if (FIRST)
        out[b] = val + b_out[0];
      else
        out[b] += val;
    }
  }
}

extern "C" void kernel_launch(void* const* d_in, const int* in_sizes, int n_in,
                              void* d_out, int out_size, void* d_ws,
                              size_t ws_size, hipStream_t stream) {
  (void)in_sizes; (void)n_in; (void)out_size; (void)ws_size;
  const float* x_i = (const float*)d_in[0];
  const float* x_j = (const float*)d_in[1];
  const int* src_i = (const int*)d_in[2];
  const int* dst_i = (const int*)d_in[3];
  const int* src_j = (const int*)d_in[4];
  const int* dst_j = (const int*)d_in[5];
  const int* ids_i = (const int*)d_in[6];
  const int* ids_j = (const int*)d_in[7];
  const float* Wn1 = (const float*)d_in[8];
  const float* Ws1 = (const float*)d_in[9];
  const float* b1 = (const float*)d_in[10];
  const float* Wn2 = (const float*)d_in[11];
  const float* Ws2 = (const float*)d_in[12];
  const float* b2 = (const float*)d_in[13];
  const float* W_out = (const float*)d_in[14];
  const float* b_out = (const float*)d_in[15];
  float* out = (float*)d_out;

  char* w = (char*)d_ws;
  int* cnt       = (int*)(w + 0);          // 200,000
  int* row_start = (int*)(w + 200704);     // 200,000
  int* cursor    = (int*)(w + 401408);     // 200,000
  int* bsum      = (int*)(w + 602112);     // 1,024
  int* csr_src   = (int*)(w + 603136);     // 3,200,000
  ushort* Wt     = (ushort*)(w + 3803136); // 131,072
  ushort* xb     = (ushort*)(w + 3934208); // 12,800,000
  ushort* aggb   = (ushort*)(w + 16734208);// 12,800,000
  float* h1      = (float*)(w + 29534464); // 51,200,000 (16B aligned)

  const int NB_SCAN = (NN + 255) / 256;  // 196

  k_wt<<<256, 256, 0, stream>>>(Wn1, Ws1, Wt);

  for (int g = 0; g < 2; ++g) {
    const float* x = g ? x_j : x_i;
    const int* src = g ? src_j : src_i;
    const int* dst = g ? dst_j : dst_i;
    const int* ids = g ? ids_j : ids_i;

    hipMemsetAsync(cnt, 0, NN * sizeof(int), stream);
    k_count<<<(NE + 255) / 256, 256, 0, stream>>>(dst, cnt);
    k_scanA<<<NB_SCAN, 256, 0, stream>>>(cnt, row_start, bsum);
    k_scanB<<<1, 64, 0, stream>>>(bsum, NB_SCAN);
    k_scanC<<<NB_SCAN, 256, 0, stream>>>(row_start, bsum, cursor);
    k_fill<<<(NE + 255) / 256, 256, 0, stream>>>(src, dst, cursor, csr_src);

    k_tobf16<<<(NN * IND / 4 + 255) / 256, 256, 0, stream>>>(x, xb, NN * IND / 4);
    k_agg1<<<(NN + 3) / 4, 256, 0, stream>>>(x, csr_src, row_start, cnt, aggb);
    k_gemm1<<<dim3((NN + 127) / 128, 2), 256, 0, stream>>>(aggb, xb, Wt, b1, h1);

    if (g == 0)
      k_layer2_out<true><<<BS / 8, 256, 0, stream>>>(
          h1, csr_src, row_start, cnt, ids, Wn2, Ws2, b2, W_out, b_out, out, 0);
    else
      k_layer2_out<false><<<BS / 8, 256, 0, stream>>>(
          h1, csr_src, row_start, cnt, ids, Wn2, Ws2, b2, W_out, b_out, out, HD);
  }
}

// Round 4
// 498.139 us; speedup vs baseline: 4.2817x; 1.4328x over previous
//
#include <hip/hip_runtime.h>

constexpr int NN = 50000;    // nodes
constexpr int NE = 800000;   // edges
constexpr int IND = 128;     // in dim
constexpr int HD = 256;      // hidden
constexpr int BS = 8192;     // seeds

typedef __attribute__((ext_vector_type(8))) short short8v;
typedef __attribute__((ext_vector_type(4))) float floatx4;

__device__ inline ushort f2b(float f) {  // f32 -> bf16 RNE
  unsigned u = __float_as_uint(f);
  unsigned r = (u + 0x7fffu + ((u >> 16) & 1u)) >> 16;
  return (ushort)r;
}
__device__ inline float b2f(ushort b) {
  return __uint_as_float((unsigned)b << 16);
}

// ---------------- in-degree count (int) ----------------
__global__ __launch_bounds__(256) void k_count(const int* __restrict__ dst,
                                               int* __restrict__ cnt) {
  int i = blockIdx.x * 256 + threadIdx.x;
  if (i < NE) atomicAdd(&cnt[dst[i]], 1);
}

// ---------------- parallel block scan ----------------
__global__ __launch_bounds__(256) void k_scanA(const int* __restrict__ cnt,
                                               int* __restrict__ row_start,
                                               int* __restrict__ bsum) {
  __shared__ int wt[4];
  int t = threadIdx.x;
  int i = blockIdx.x * 256 + t;
  int v = (i < NN) ? cnt[i] : 0;
  int x = v;
#pragma unroll
  for (int d = 1; d < 64; d <<= 1) {
    int y = __shfl_up(x, d);
    if ((t & 63) >= d) x += y;
  }
  if ((t & 63) == 63) wt[t >> 6] = x;
  __syncthreads();
  if (t == 0) {
    int run = 0;
#pragma unroll
    for (int j = 0; j < 4; ++j) { int tv = wt[j]; wt[j] = run; run += tv; }
    bsum[blockIdx.x] = run;
  }
  __syncthreads();
  if (i < NN) row_start[i] = x - v + wt[t >> 6];
}

__global__ __launch_bounds__(256) void k_scanB(int* __restrict__ bsum, int nb) {
  __shared__ int wt[4];
  int t = threadIdx.x;
  int v = (t < nb) ? bsum[t] : 0;
  int x = v;
#pragma unroll
  for (int d = 1; d < 64; d <<= 1) {
    int y = __shfl_up(x, d);
    if ((t & 63) >= d) x += y;
  }
  if ((t & 63) == 63) wt[t >> 6] = x;
  __syncthreads();
  if (t == 0) {
    int run = 0;
#pragma unroll
    for (int j = 0; j < 4; ++j) { int tv = wt[j]; wt[j] = run; run += tv; }
  }
  __syncthreads();
  if (t < nb) bsum[t] = x - v + wt[t >> 6];
}

__global__ __launch_bounds__(256) void k_scanC(int* __restrict__ row_start,
                                               const int* __restrict__ bsum,
                                               int* __restrict__ cursor) {
  int i = blockIdx.x * 256 + threadIdx.x;
  if (i < NN) {
    int v = row_start[i] + bsum[i >> 8];
    row_start[i] = v;
    cursor[i] = v;
  }
}

// ---------------- fill CSR (bump-allocate) ----------------
__global__ __launch_bounds__(256) void k_fill(const int* __restrict__ src,
                                              const int* __restrict__ dst,
                                              int* __restrict__ cursor,
                                              int* __restrict__ csr_src) {
  int i = blockIdx.x * 256 + threadIdx.x;
  if (i < NE) {
    int pos = atomicAdd(&cursor[dst[i]], 1);
    csr_src[pos] = src[i];
  }
}

// ---------------- f32 -> bf16 convert ----------------
__global__ __launch_bounds__(256) void k_tobf16(const float* __restrict__ x,
                                                ushort* __restrict__ o, int n4) {
  int i = blockIdx.x * 256 + threadIdx.x;
  if (i < n4) {
    float4 v = *(const float4*)(x + i * 4);
    ushort4 u;
    u.x = f2b(v.x); u.y = f2b(v.y); u.z = f2b(v.z); u.w = f2b(v.w);
    *(ushort4*)(o + i * 4) = u;
  }
}

// ---------------- layer-1 weights: Wt[n][k] bf16, k<128->Wn1 ----------------
__global__ __launch_bounds__(256) void k_wt(const float* __restrict__ Wn1,
                                            const float* __restrict__ Ws1,
                                            ushort* __restrict__ Wt) {
  int i = blockIdx.x * 256 + threadIdx.x;  // 65536
  int n = i >> 8, k = i & 255;
  float v = (k < 128) ? Wn1[k * HD + n] : Ws1[(k - 128) * HD + n];
  Wt[n * 256 + k] = f2b(v);
}

// ---------------- layer-2 weights: W2[n][k] split hi/lo, k<256->Wn2 ----------
__global__ __launch_bounds__(256) void k_w2(const float* __restrict__ Wn2,
                                            const float* __restrict__ Ws2,
                                            ushort* __restrict__ Whi,
                                            ushort* __restrict__ Wlo) {
  int i = blockIdx.x * 256 + threadIdx.x;  // 131072
  int n = i >> 9, k = i & 511;
  float v = (k < 256) ? Wn2[k * HD + n] : Ws2[(k - 256) * HD + n];
  ushort hi = f2b(v);
  Whi[n * 512 + k] = hi;
  Wlo[n * 512 + k] = f2b(v - b2f(hi));
}

// ---------------- layer-1 pull aggregation (ILP-4) ----------------
__global__ __launch_bounds__(256) void k_agg1(const float* __restrict__ x,
                                              const int* __restrict__ csr_src,
                                              const int* __restrict__ row_start,
                                              const int* __restrict__ cnt,
                                              ushort* __restrict__ aggb) {
  int w = threadIdx.x >> 6, l = threadIdx.x & 63;
  int node = blockIdx.x * 4 + w;
  if (node >= NN) return;
  int st = row_start[node], deg = cnt[node];
  float a0 = 0.f, a1 = 0.f;
  int e = 0;
  for (; e + 4 <= deg; e += 4) {
    int s0 = csr_src[st + e + 0], s1 = csr_src[st + e + 1];
    int s2 = csr_src[st + e + 2], s3 = csr_src[st + e + 3];
    float2 v0 = *(const float2*)(x + s0 * IND + 2 * l);
    float2 v1 = *(const float2*)(x + s1 * IND + 2 * l);
    float2 v2 = *(const float2*)(x + s2 * IND + 2 * l);
    float2 v3 = *(const float2*)(x + s3 * IND + 2 * l);
    a0 += v0.x + v1.x + v2.x + v3.x;
    a1 += v0.y + v1.y + v2.y + v3.y;
  }
  for (; e < deg; ++e) {
    int s = csr_src[st + e];
    float2 v = *(const float2*)(x + s * IND + 2 * l);
    a0 += v.x; a1 += v.y;
  }
  float inv = 1.f / (float)max(deg, 1);
  ushort2 u;
  u.x = f2b(a0 * inv); u.y = f2b(a1 * inv);
  *(ushort2*)(aggb + node * IND + 2 * l) = u;
}

// ---------------- layer-1 MFMA GEMM: h1 = relu([agg|x] @ [Wn1;Ws1] + b1) ----
__global__ __launch_bounds__(256) void k_gemm1(const ushort* __restrict__ aggb,
                                               const ushort* __restrict__ xb,
                                               const ushort* __restrict__ Wt,
                                               const float* __restrict__ b1,
                                               float* __restrict__ h1) {
  __shared__ ushort Al[128 * 32];
  __shared__ ushort Bl[128 * 32];
  const int t = threadIdx.x;
  const int row0 = blockIdx.x * 128, col0 = blockIdx.y * 128;
  const int w = t >> 6, l = t & 63;
  const int wm = w & 1, wn = w >> 1;
  floatx4 acc[4][4];
#pragma unroll
  for (int i = 0; i < 4; ++i)
#pragma unroll
    for (int j = 0; j < 4; ++j) acc[i][j] = (floatx4){0.f, 0.f, 0.f, 0.f};

  for (int kk = 0; kk < 256; kk += 32) {
    const ushort* Abase = (kk < 128) ? (aggb + kk) : (xb + (kk - 128));
#pragma unroll
    for (int s = t; s < 512; s += 256) {
      int r = s >> 2, c = s & 3;
      int grow = row0 + r;
      short8v v = {0, 0, 0, 0, 0, 0, 0, 0};
      if (grow < NN) v = *(const short8v*)(Abase + grow * IND + c * 8);
      *(short8v*)(Al + r * 32 + ((c ^ (r & 3)) * 8)) = v;
    }
#pragma unroll
    for (int s = t; s < 512; s += 256) {
      int r = s >> 2, c = s & 3;
      short8v v = *(const short8v*)(Wt + (col0 + r) * 256 + kk + c * 8);
      *(short8v*)(Bl + r * 32 + ((c ^ (r & 3)) * 8)) = v;
    }
    __syncthreads();
    const int rA = l & 15, g = l >> 4;
    short8v af[4], bf[4];
#pragma unroll
    for (int i = 0; i < 4; ++i) {
      int r = wm * 64 + i * 16 + rA;
      af[i] = *(const short8v*)(Al + r * 32 + ((g ^ (r & 3)) * 8));
    }
#pragma unroll
    for (int j = 0; j < 4; ++j) {
      int r = wn * 64 + j * 16 + rA;
      bf[j] = *(const short8v*)(Bl + r * 32 + ((g ^ (r & 3)) * 8));
    }
#pragma unroll
    for (int i = 0; i < 4; ++i)
#pragma unroll
      for (int j = 0; j < 4; ++j)
        acc[i][j] = __builtin_amdgcn_mfma_f32_16x16x32_bf16(af[i], bf[j],
                                                            acc[i][j], 0, 0, 0);
    __syncthreads();
  }
  const int rD = l >> 4, cD = l & 15;
#pragma unroll
  for (int j = 0; j < 4; ++j) {
    int col = col0 + wn * 64 + j * 16 + cD;
    float bias = b1[col];
#pragma unroll
    for (int i = 0; i < 4; ++i) {
      int rbase = row0 + wm * 64 + i * 16 + rD * 4;
#pragma unroll
      for (int rr = 0; rr < 4; ++rr) {
        int row = rbase + rr;
        if (row < NN) h1[row * HD + col] = fmaxf(acc[i][j][rr] + bias, 0.f);
      }
    }
  }
}

// ---------------- layer-2 aggregation @ seeds -> compact A (hi/lo) ------------
// one block per seed; 4 waves stride edges; lane owns 4 dims
__global__ __launch_bounds__(256) void k_agg2(
    const float* __restrict__ h1, const int* __restrict__ csr_src,
    const int* __restrict__ row_start, const int* __restrict__ cnt,
    const int* __restrict__ ids, ushort* __restrict__ Ahi,
    ushort* __restrict__ Alo) {
  __shared__ float red[4][HD];
  const int b = blockIdx.x;
  const int node = ids[b];
  const int st = row_start[node], deg = cnt[node];
  const int w = threadIdx.x >> 6, l = threadIdx.x & 63;
  float4 a = {0.f, 0.f, 0.f, 0.f};
  for (int e = w; e < deg; e += 4) {
    int s = csr_src[st + e];
    float4 v = *(const float4*)(h1 + s * HD + l * 4);
    a.x += v.x; a.y += v.y; a.z += v.z; a.w += v.w;
  }
  *(float4*)&red[w][l * 4] = a;
  __syncthreads();
  const int t = threadIdx.x;
  float s = (red[0][t] + red[1][t]) + (red[2][t] + red[3][t]);
  s *= 1.f / (float)max(deg, 1);
  ushort hi = f2b(s);
  Ahi[b * 512 + t] = hi;
  Alo[b * 512 + t] = f2b(s - b2f(hi));
  float sv = h1[node * HD + t];
  ushort shi = f2b(sv);
  Ahi[b * 512 + 256 + t] = shi;
  Alo[b * 512 + 256 + t] = f2b(sv - b2f(shi));
}

// ---------------- layer-2 MFMA GEMM (split-bf16): h2 = A @ W2 + b2 ----------
// M=8192 N=256 K=512, tile 64x128, 4 waves (2x2)
__global__ __launch_bounds__(256) void k_head(const ushort* __restrict__ Ahi,
                                              const ushort* __restrict__ Alo,
                                              const ushort* __restrict__ Whi,
                                              const ushort* __restrict__ Wlo,
                                              const float* __restrict__ b2,
                                              float* __restrict__ h2) {
  __shared__ ushort Ahl[64 * 32];
  __shared__ ushort All[64 * 32];
  __shared__ ushort Bhl[128 * 32];
  __shared__ ushort Bll[128 * 32];
  const int t = threadIdx.x;
  const int row0 = blockIdx.x * 64, col0 = blockIdx.y * 128;
  const int w = t >> 6, l = t & 63;
  const int wm = w & 1, wn = w >> 1;
  floatx4 acc[2][4];
#pragma unroll
  for (int i = 0; i < 2; ++i)
#pragma unroll
    for (int j = 0; j < 4; ++j) acc[i][j] = (floatx4){0.f, 0.f, 0.f, 0.f};

  for (int kk = 0; kk < 512; kk += 32) {
    {
      int s = t & 255;
      if (s < 256) {
        int r = s >> 2, c = s & 3;
        int sw = (c ^ (r & 3)) * 8;
        *(short8v*)(Ahl + r * 32 + sw) =
            *(const short8v*)(Ahi + (row0 + r) * 512 + kk + c * 8);
        *(short8v*)(All + r * 32 + sw) =
            *(const short8v*)(Alo + (row0 + r) * 512 + kk + c * 8);
      }
    }
#pragma unroll
    for (int s = t; s < 512; s += 256) {
      int r = s >> 2, c = s & 3;
      int sw = (c ^ (r & 3)) * 8;
      *(short8v*)(Bhl + r * 32 + sw) =
          *(const short8v*)(Whi + (col0 + r) * 512 + kk + c * 8);
      *(short8v*)(Bll + r * 32 + sw) =
          *(const short8v*)(Wlo + (col0 + r) * 512 + kk + c * 8);
    }
    __syncthreads();
    const int rA = l & 15, g = l >> 4;
    short8v ah[2], al[2], bh[4], bl[4];
#pragma unroll
    for (int i = 0; i < 2; ++i) {
      int r = wm * 32 + i * 16 + rA;
      int sw = (g ^ (r & 3)) * 8;
      ah[i] = *(const short8v*)(Ahl + r * 32 + sw);
      al[i] = *(const short8v*)(All + r * 32 + sw);
    }
#pragma unroll
    for (int j = 0; j < 4; ++j) {
      int r = wn * 64 + j * 16 + rA;
      int sw = (g ^ (r & 3)) * 8;
      bh[j] = *(const short8v*)(Bhl + r * 32 + sw);
      bl[j] = *(const short8v*)(Bll + r * 32 + sw);
    }
#pragma unroll
    for (int i = 0; i < 2; ++i)
#pragma unroll
      for (int j = 0; j < 4; ++j) {
        acc[i][j] = __builtin_amdgcn_mfma_f32_16x16x32_bf16(ah[i], bh[j],
                                                            acc[i][j], 0, 0, 0);
        acc[i][j] = __builtin_amdgcn_mfma_f32_16x16x32_bf16(ah[i], bl[j],
                                                            acc[i][j], 0, 0, 0);
        acc[i][j] = __builtin_amdgcn_mfma_f32_16x16x32_bf16(al[i], bh[j],
                                                            acc[i][j], 0, 0, 0);
      }
    __syncthreads();
  }
  const int rD = l >> 4, cD = l & 15;
#pragma unroll
  for (int j = 0; j < 4; ++j) {
    int col = col0 + wn * 64 + j * 16 + cD;
    float bias = b2[col];
#pragma unroll
    for (int i = 0; i < 2; ++i) {
      int rbase = row0 + wm * 32 + i * 16 + rD * 4;
#pragma unroll
      for (int rr = 0; rr < 4; ++rr) {
        h2[(rbase + rr) * HD + col] = acc[i][j][rr] + bias;
      }
    }
  }
}

// ---------------- l2norm + head dot ----------------
template <bool FIRST>
__global__ __launch_bounds__(256) void k_out(const float* __restrict__ h2,
                                             const float* __restrict__ W_out,
                                             const float* __restrict__ b_out,
                                             float* __restrict__ out, int off) {
  int w = threadIdx.x >> 6, l = threadIdx.x & 63;
  int b = blockIdx.x * 4 + w;
  float4 v = *(const float4*)(h2 + b * HD + l * 4);
  float4 wo = *(const float4*)(W_out + off + l * 4);
  float ss = v.x * v.x + v.y * v.y + v.z * v.z + v.w * v.w;
  float dp = v.x * wo.x + v.y * wo.y + v.z * wo.z + v.w * wo.w;
#pragma unroll
  for (int o = 32; o; o >>= 1) {
    ss += __shfl_down(ss, o);
    dp += __shfl_down(dp, o);
  }
  if (l == 0) {
    float val = dp / fmaxf(sqrtf(ss), 1e-12f);
    if (FIRST)
      out[b] = val + b_out[0];
    else
      out[b] += val;
  }
}

extern "C" void kernel_launch(void* const* d_in, const int* in_sizes, int n_in,
                              void* d_out, int out_size, void* d_ws,
                              size_t ws_size, hipStream_t stream) {
  (void)in_sizes; (void)n_in; (void)out_size; (void)ws_size;
  const float* x_i = (const float*)d_in[0];
  const float* x_j = (const float*)d_in[1];
  const int* src_i = (const int*)d_in[2];
  const int* dst_i = (const int*)d_in[3];
  const int* src_j = (const int*)d_in[4];
  const int* dst_j = (const int*)d_in[5];
  const int* ids_i = (const int*)d_in[6];
  const int* ids_j = (const int*)d_in[7];
  const float* Wn1 = (const float*)d_in[8];
  const float* Ws1 = (const float*)d_in[9];
  const float* b1 = (const float*)d_in[10];
  const float* Wn2 = (const float*)d_in[11];
  const float* Ws2 = (const float*)d_in[12];
  const float* b2 = (const float*)d_in[13];
  const float* W_out = (const float*)d_in[14];
  const float* b_out = (const float*)d_in[15];
  float* out = (float*)d_out;

  char* w = (char*)d_ws;
  int* cnt       = (int*)(w + 0);
  int* row_start = (int*)(w + 200704);
  int* cursor    = (int*)(w + 401408);
  int* bsum      = (int*)(w + 602112);
  int* csr_src   = (int*)(w + 603136);
  ushort* Wt     = (ushort*)(w + 3803136);
  ushort* W2hi   = (ushort*)(w + 3934208);
  ushort* W2lo   = (ushort*)(w + 4196352);
  ushort* xb     = (ushort*)(w + 4458496);
  ushort* aggb   = (ushort*)(w + 17258496);
  ushort* Ahi    = (ushort*)(w + 30058496);
  ushort* Alo    = (ushort*)(w + 38447104);
  float* h2      = (float*)(w + 46835712);
  float* h1      = (float*)(w + 55224320);

  const int NB_SCAN = (NN + 255) / 256;  // 196

  k_wt<<<256, 256, 0, stream>>>(Wn1, Ws1, Wt);
  k_w2<<<512, 256, 0, stream>>>(Wn2, Ws2, W2hi, W2lo);

  for (int g = 0; g < 2; ++g) {
    const float* x = g ? x_j : x_i;
    const int* src = g ? src_j : src_i;
    const int* dst = g ? dst_j : dst_i;
    const int* ids = g ? ids_j : ids_i;

    hipMemsetAsync(cnt, 0, NN * sizeof(int), stream);
    k_count<<<(NE + 255) / 256, 256, 0, stream>>>(dst, cnt);
    k_scanA<<<NB_SCAN, 256, 0, stream>>>(cnt, row_start, bsum);
    k_scanB<<<1, 256, 0, stream>>>(bsum, NB_SCAN);
    k_scanC<<<NB_SCAN, 256, 0, stream>>>(row_start, bsum, cursor);
    k_fill<<<(NE + 255) / 256, 256, 0, stream>>>(src, dst, cursor, csr_src);

    k_tobf16<<<(NN * IND / 4 + 255) / 256, 256, 0, stream>>>(x, xb,
                                                             NN * IND / 4);
    k_agg1<<<(NN + 3) / 4, 256, 0, stream>>>(x, csr_src, row_start, cnt, aggb);
    k_gemm1<<<dim3((NN + 127) / 128, 2), 256, 0, stream>>>(aggb, xb, Wt, b1,
                                                           h1);
    k_agg2<<<BS, 256, 0, stream>>>(h1, csr_src, row_start, cnt, ids, Ahi, Alo);
    k_head<<<dim3(BS / 64, 2), 256, 0, stream>>>(Ahi, Alo, W2hi, W2lo, b2, h2);
    if (g == 0)
      k_out<true><<<BS / 4, 256, 0, stream>>>(h2, W_out, b_out, out, 0);
    else
      k_out<false><<<BS / 4, 256, 0, stream>>>(h2, W_out, b_out, out, HD);
  }
}

// Round 5
// 418.558 us; speedup vs baseline: 5.0957x; 1.1901x over previous
//
#include <hip/hip_runtime.h>

constexpr int NN = 50000;     // nodes per graph
constexpr int NE = 800000;    // edges per graph
constexpr int IND = 128;      // in dim
constexpr int HD = 256;       // hidden
constexpr int BS = 8192;      // seeds per graph
constexpr int NPAD = 50176;   // 196*256, block-aligned padded node count

typedef __attribute__((ext_vector_type(8))) short short8v;
typedef __attribute__((ext_vector_type(4))) float floatx4;

__device__ inline ushort f2b(float f) {  // f32 -> bf16 RNE
  unsigned u = __float_as_uint(f);
  unsigned r = (u + 0x7fffu + ((u >> 16) & 1u)) >> 16;
  return (ushort)r;
}
__device__ inline float b2f(ushort b) {
  return __uint_as_float((unsigned)b << 16);
}

// ---------------- in-degree count, both graphs, ILP-4 ----------------
__global__ __launch_bounds__(256) void k_count(const int* __restrict__ dst_i,
                                               const int* __restrict__ dst_j,
                                               int* __restrict__ cnt2) {
  int base = (blockIdx.x * 256 + threadIdx.x) * 4;
  if (base >= 2 * NE) return;
  int g = base >= NE;
  const int* dst = g ? dst_j : dst_i;
  int e = base - g * NE;
  int gofs = g * NPAD;
  int d0 = dst[e + 0], d1 = dst[e + 1], d2 = dst[e + 2], d3 = dst[e + 3];
  atomicAdd(&cnt2[gofs + d0], 1);
  atomicAdd(&cnt2[gofs + d1], 1);
  atomicAdd(&cnt2[gofs + d2], 1);
  atomicAdd(&cnt2[gofs + d3], 1);
}

// ---------------- parallel block scan (392 blocks over 2*NPAD) ----------------
__global__ __launch_bounds__(256) void k_scanA(const int* __restrict__ cnt2,
                                               int* __restrict__ row_start2,
                                               int* __restrict__ bsum) {
  __shared__ int wt[4];
  int t = threadIdx.x;
  int i = blockIdx.x * 256 + t;
  int v = cnt2[i];
  int x = v;
#pragma unroll
  for (int d = 1; d < 64; d <<= 1) {
    int y = __shfl_up(x, d);
    if ((t & 63) >= d) x += y;
  }
  if ((t & 63) == 63) wt[t >> 6] = x;
  __syncthreads();
  if (t == 0) {
    int run = 0;
#pragma unroll
    for (int j = 0; j < 4; ++j) { int tv = wt[j]; wt[j] = run; run += tv; }
    bsum[blockIdx.x] = run;
  }
  __syncthreads();
  row_start2[i] = x - v + wt[t >> 6];
}

// two independent 196-element exclusive scans (one per graph)
__global__ __launch_bounds__(256) void k_scanB(int* __restrict__ bsum) {
  __shared__ int wt[4];
  int t = threadIdx.x;
  int base = blockIdx.x * 196;
  int v = (t < 196) ? bsum[base + t] : 0;
  int x = v;
#pragma unroll
  for (int d = 1; d < 64; d <<= 1) {
    int y = __shfl_up(x, d);
    if ((t & 63) >= d) x += y;
  }
  if ((t & 63) == 63) wt[t >> 6] = x;
  __syncthreads();
  if (t == 0) {
    int run = 0;
#pragma unroll
    for (int j = 0; j < 4; ++j) { int tv = wt[j]; wt[j] = run; run += tv; }
  }
  __syncthreads();
  if (t < 196) bsum[base + t] = x - v + wt[t >> 6];
}

__global__ __launch_bounds__(256) void k_scanC(int* __restrict__ row_start2,
                                               const int* __restrict__ bsum,
                                               int* __restrict__ cursor2) {
  int i = blockIdx.x * 256 + threadIdx.x;  // < 2*NPAD
  int v = row_start2[i] + bsum[i >> 8] + ((i >= NPAD) ? NE : 0);
  row_start2[i] = v;
  cursor2[i] = v;
}

// ---------------- fill CSR (bump-allocate), both graphs, ILP-4 ----------------
__global__ __launch_bounds__(256) void k_fill(const int* __restrict__ src_i,
                                              const int* __restrict__ dst_i,
                                              const int* __restrict__ src_j,
                                              const int* __restrict__ dst_j,
                                              int* __restrict__ cursor2,
                                              int* __restrict__ csr_src2) {
  int base = (blockIdx.x * 256 + threadIdx.x) * 4;
  if (base >= 2 * NE) return;
  int g = base >= NE;
  const int* src = g ? src_j : src_i;
  const int* dst = g ? dst_j : dst_i;
  int e = base - g * NE;
  int gofs = g * NPAD;
  int d0 = dst[e + 0], d1 = dst[e + 1], d2 = dst[e + 2], d3 = dst[e + 3];
  int s0 = src[e + 0], s1 = src[e + 1], s2 = src[e + 2], s3 = src[e + 3];
  int p0 = atomicAdd(&cursor2[gofs + d0], 1);
  int p1 = atomicAdd(&cursor2[gofs + d1], 1);
  int p2 = atomicAdd(&cursor2[gofs + d2], 1);
  int p3 = atomicAdd(&cursor2[gofs + d3], 1);
  csr_src2[p0] = s0;
  csr_src2[p1] = s1;
  csr_src2[p2] = s2;
  csr_src2[p3] = s3;
}

// ---------------- f32 -> bf16 convert, both graphs ----------------
__global__ __launch_bounds__(256) void k_tobf16(const float* __restrict__ x_i,
                                                const float* __restrict__ x_j,
                                                ushort* __restrict__ xb2) {
  int i = blockIdx.x * 256 + threadIdx.x;  // < 3.2M
  int e4 = i * 4;
  int g = e4 >= NN * IND;
  const float* xp = g ? x_j : x_i;
  float4 v = *(const float4*)(xp + (e4 - g * NN * IND));
  ushort4 u;
  u.x = f2b(v.x); u.y = f2b(v.y); u.z = f2b(v.z); u.w = f2b(v.w);
  *(ushort4*)(xb2 + e4) = u;
}

// ---------------- layer-1 weights: Wt[n][k] bf16, k<128->Wn1 ----------------
__global__ __launch_bounds__(256) void k_wt(const float* __restrict__ Wn1,
                                            const float* __restrict__ Ws1,
                                            ushort* __restrict__ Wt) {
  int i = blockIdx.x * 256 + threadIdx.x;  // 65536
  int n = i >> 8, k = i & 255;
  float v = (k < 128) ? Wn1[k * HD + n] : Ws1[(k - 128) * HD + n];
  Wt[n * 256 + k] = f2b(v);
}

// ---------------- layer-2 weights: W2[n][k] split hi/lo, k<256->Wn2 ----------
__global__ __launch_bounds__(256) void k_w2(const float* __restrict__ Wn2,
                                            const float* __restrict__ Ws2,
                                            ushort* __restrict__ Whi,
                                            ushort* __restrict__ Wlo) {
  int i = blockIdx.x * 256 + threadIdx.x;  // 131072
  int n = i >> 9, k = i & 511;
  float v = (k < 256) ? Wn2[k * HD + n] : Ws2[(k - 256) * HD + n];
  ushort hi = f2b(v);
  Whi[n * 512 + k] = hi;
  Wlo[n * 512 + k] = f2b(v - b2f(hi));
}

// ---------------- layer-1 pull aggregation from bf16 (ILP-4) ----------------
__global__ __launch_bounds__(256) void k_agg1(const ushort* __restrict__ xb2,
                                              const int* __restrict__ csr_src2,
                                              const int* __restrict__ row_start2,
                                              const int* __restrict__ cnt2,
                                              ushort* __restrict__ aggb2) {
  int w = threadIdx.x >> 6, l = threadIdx.x & 63;
  int n = blockIdx.x * 4 + w;  // < 2*NN exactly
  int g = n >= NN;
  int nl = n - g * NN;
  int st = row_start2[g * NPAD + nl], deg = cnt2[g * NPAD + nl];
  const ushort* xb = xb2 + g * NN * IND;
  float a0 = 0.f, a1 = 0.f;
  int e = 0;
  for (; e + 4 <= deg; e += 4) {
    int s0 = csr_src2[st + e + 0], s1 = csr_src2[st + e + 1];
    int s2 = csr_src2[st + e + 2], s3 = csr_src2[st + e + 3];
    ushort2 u0 = *(const ushort2*)(xb + s0 * IND + 2 * l);
    ushort2 u1 = *(const ushort2*)(xb + s1 * IND + 2 * l);
    ushort2 u2 = *(const ushort2*)(xb + s2 * IND + 2 * l);
    ushort2 u3 = *(const ushort2*)(xb + s3 * IND + 2 * l);
    a0 += b2f(u0.x) + b2f(u1.x) + b2f(u2.x) + b2f(u3.x);
    a1 += b2f(u0.y) + b2f(u1.y) + b2f(u2.y) + b2f(u3.y);
  }
  for (; e < deg; ++e) {
    int s = csr_src2[st + e];
    ushort2 u = *(const ushort2*)(xb + s * IND + 2 * l);
    a0 += b2f(u.x);
    a1 += b2f(u.y);
  }
  float inv = 1.f / (float)max(deg, 1);
  ushort2 u;
  u.x = f2b(a0 * inv);
  u.y = f2b(a1 * inv);
  *(ushort2*)(aggb2 + (g * NN + nl) * IND + 2 * l) = u;
}

// ---------------- layer-1 MFMA GEMM: h1b = relu([agg|x] @ [Wn1;Ws1] + b1) ----
// both graphs: grid.x = 784 (392/graph), grid.y = 2 (col halves)
__global__ __launch_bounds__(256) void k_gemm1(const ushort* __restrict__ aggb2,
                                               const ushort* __restrict__ xb2,
                                               const ushort* __restrict__ Wt,
                                               const float* __restrict__ b1,
                                               ushort* __restrict__ h1b2) {
  __shared__ ushort Al[128 * 32];
  __shared__ ushort Bl[128 * 32];
  const int t = threadIdx.x;
  const int g = blockIdx.x >= 392;
  const int row0 = (blockIdx.x - g * 392) * 128, col0 = blockIdx.y * 128;
  const ushort* aggb = aggb2 + g * NN * IND;
  const ushort* xb = xb2 + g * NN * IND;
  ushort* h1b = h1b2 + g * NN * HD;
  const int w = t >> 6, l = t & 63;
  const int wm = w & 1, wn = w >> 1;
  floatx4 acc[4][4];
#pragma unroll
  for (int i = 0; i < 4; ++i)
#pragma unroll
    for (int j = 0; j < 4; ++j) acc[i][j] = (floatx4){0.f, 0.f, 0.f, 0.f};

  for (int kk = 0; kk < 256; kk += 32) {
    const ushort* Abase = (kk < 128) ? (aggb + kk) : (xb + (kk - 128));
#pragma unroll
    for (int s = t; s < 512; s += 256) {
      int r = s >> 2, c = s & 3;
      int grow = row0 + r;
      short8v v = {0, 0, 0, 0, 0, 0, 0, 0};
      if (grow < NN) v = *(const short8v*)(Abase + grow * IND + c * 8);
      *(short8v*)(Al + r * 32 + ((c ^ (r & 3)) * 8)) = v;
    }
#pragma unroll
    for (int s = t; s < 512; s += 256) {
      int r = s >> 2, c = s & 3;
      short8v v = *(const short8v*)(Wt + (col0 + r) * 256 + kk + c * 8);
      *(short8v*)(Bl + r * 32 + ((c ^ (r & 3)) * 8)) = v;
    }
    __syncthreads();
    const int rA = l & 15, gg = l >> 4;
    short8v af[4], bf[4];
#pragma unroll
    for (int i = 0; i < 4; ++i) {
      int r = wm * 64 + i * 16 + rA;
      af[i] = *(const short8v*)(Al + r * 32 + ((gg ^ (r & 3)) * 8));
    }
#pragma unroll
    for (int j = 0; j < 4; ++j) {
      int r = wn * 64 + j * 16 + rA;
      bf[j] = *(const short8v*)(Bl + r * 32 + ((gg ^ (r & 3)) * 8));
    }
#pragma unroll
    for (int i = 0; i < 4; ++i)
#pragma unroll
      for (int j = 0; j < 4; ++j)
        acc[i][j] = __builtin_amdgcn_mfma_f32_16x16x32_bf16(af[i], bf[j],
                                                            acc[i][j], 0, 0, 0);
    __syncthreads();
  }
  const int rD = l >> 4, cD = l & 15;
#pragma unroll
  for (int j = 0; j < 4; ++j) {
    int col = col0 + wn * 64 + j * 16 + cD;
    float bias = b1[col];
#pragma unroll
    for (int i = 0; i < 4; ++i) {
      int rbase = row0 + wm * 64 + i * 16 + rD * 4;
#pragma unroll
      for (int rr = 0; rr < 4; ++rr) {
        int row = rbase + rr;
        if (row < NN)
          h1b[row * HD + col] = f2b(fmaxf(acc[i][j][rr] + bias, 0.f));
      }
    }
  }
}

// ---------------- layer-2 aggregation @ seeds -> compact bf16 A --------------
// grid 16384: one block per seed (both graphs); 4 waves stride edges
__global__ __launch_bounds__(256) void k_agg2(
    const ushort* __restrict__ h1b2, const int* __restrict__ csr_src2,
    const int* __restrict__ row_start2, const int* __restrict__ cnt2,
    const int* __restrict__ ids_i, const int* __restrict__ ids_j,
    ushort* __restrict__ A2) {
  __shared__ float red[4][HD];
  const int b = blockIdx.x;
  const int g = b >= BS;
  const int node = (g ? ids_j : ids_i)[b - g * BS];
  const int st = row_start2[g * NPAD + node], deg = cnt2[g * NPAD + node];
  const ushort* h1b = h1b2 + g * NN * HD;
  const int w = threadIdx.x >> 6, l = threadIdx.x & 63;
  float a0 = 0.f, a1 = 0.f, a2 = 0.f, a3 = 0.f;
  for (int e = w; e < deg; e += 4) {
    int s = csr_src2[st + e];
    ushort4 u = *(const ushort4*)(h1b + s * HD + l * 4);
    a0 += b2f(u.x); a1 += b2f(u.y); a2 += b2f(u.z); a3 += b2f(u.w);
  }
  red[w][l * 4 + 0] = a0;
  red[w][l * 4 + 1] = a1;
  red[w][l * 4 + 2] = a2;
  red[w][l * 4 + 3] = a3;
  __syncthreads();
  const int t = threadIdx.x;
  float s = (red[0][t] + red[1][t]) + (red[2][t] + red[3][t]);
  s *= 1.f / (float)max(deg, 1);
  A2[b * 512 + t] = f2b(s);
  A2[b * 512 + 256 + t] = h1b[node * HD + t];  // exact bf16 copy
}

// ---------------- layer-2 MFMA GEMM: h2 = A @ [Whi+Wlo] + b2 ----------------
// M=16384 N=256 K=512, tile 64x128, grid (256, 2)
__global__ __launch_bounds__(256) void k_head(const ushort* __restrict__ A2,
                                              const ushort* __restrict__ Whi,
                                              const ushort* __restrict__ Wlo,
                                              const float* __restrict__ b2,
                                              float* __restrict__ h2) {
  __shared__ ushort Ahl[64 * 32];
  __shared__ ushort Bhl[128 * 32];
  __shared__ ushort Bll[128 * 32];
  const int t = threadIdx.x;
  const int row0 = blockIdx.x * 64, col0 = blockIdx.y * 128;
  const int w = t >> 6, l = t & 63;
  const int wm = w & 1, wn = w >> 1;
  floatx4 acc[2][4];
#pragma unroll
  for (int i = 0; i < 2; ++i)
#pragma unroll
    for (int j = 0; j < 4; ++j) acc[i][j] = (floatx4){0.f, 0.f, 0.f, 0.f};

  for (int kk = 0; kk < 512; kk += 32) {
    if (t < 256) {
      int r = t >> 2, c = t & 3;
      int sw = (c ^ (r & 3)) * 8;
      *(short8v*)(Ahl + r * 32 + sw) =
          *(const short8v*)(A2 + (row0 + r) * 512 + kk + c * 8);
    }
#pragma unroll
    for (int s = t; s < 512; s += 256) {
      int r = s >> 2, c = s & 3;
      int sw = (c ^ (r & 3)) * 8;
      *(short8v*)(Bhl + r * 32 + sw) =
          *(const short8v*)(Whi + (col0 + r) * 512 + kk + c * 8);
      *(short8v*)(Bll + r * 32 + sw) =
          *(const short8v*)(Wlo + (col0 + r) * 512 + kk + c * 8);
    }
    __syncthreads();
    const int rA = l & 15, gg = l >> 4;
    short8v ah[2], bh[4], bl[4];
#pragma unroll
    for (int i = 0; i < 2; ++i) {
      int r = wm * 32 + i * 16 + rA;
      ah[i] = *(const short8v*)(Ahl + r * 32 + ((gg ^ (r & 3)) * 8));
    }
#pragma unroll
    for (int j = 0; j < 4; ++j) {
      int r = wn * 64 + j * 16 + rA;
      int sw = (gg ^ (r & 3)) * 8;
      bh[j] = *(const short8v*)(Bhl + r * 32 + sw);
      bl[j] = *(const short8v*)(Bll + r * 32 + sw);
    }
#pragma unroll
    for (int i = 0; i < 2; ++i)
#pragma unroll
      for (int j = 0; j < 4; ++j) {
        acc[i][j] = __builtin_amdgcn_mfma_f32_16x16x32_bf16(ah[i], bh[j],
                                                            acc[i][j], 0, 0, 0);
        acc[i][j] = __builtin_amdgcn_mfma_f32_16x16x32_bf16(ah[i], bl[j],
                                                            acc[i][j], 0, 0, 0);
      }
    __syncthreads();
  }
  const int rD = l >> 4, cD = l & 15;
#pragma unroll
  for (int j = 0; j < 4; ++j) {
    int col = col0 + wn * 64 + j * 16 + cD;
    float bias = b2[col];
#pragma unroll
    for (int i = 0; i < 2; ++i) {
      int rbase = row0 + wm * 32 + i * 16 + rD * 4;
#pragma unroll
      for (int rr = 0; rr < 4; ++rr) {
        h2[(rbase + rr) * HD + col] = acc[i][j][rr] + bias;
      }
    }
  }
}

// ---------------- l2norm + head dot (both halves fused) ----------------
__global__ __launch_bounds__(256) void k_out(const float* __restrict__ h2,
                                             const float* __restrict__ W_out,
                                             const float* __restrict__ b_out,
                                             float* __restrict__ out) {
  int w = threadIdx.x >> 6, l = threadIdx.x & 63;
  int s = blockIdx.x * 4 + w;  // seed, < 8192
  float4 vi = *(const float4*)(h2 + s * HD + l * 4);
  float4 vj = *(const float4*)(h2 + (s + BS) * HD + l * 4);
  float4 wi = *(const float4*)(W_out + l * 4);
  float4 wj = *(const float4*)(W_out + 256 + l * 4);
  float ssi = vi.x * vi.x + vi.y * vi.y + vi.z * vi.z + vi.w * vi.w;
  float dpi = vi.x * wi.x + vi.y * wi.y + vi.z * wi.z + vi.w * wi.w;
  float ssj = vj.x * vj.x + vj.y * vj.y + vj.z * vj.z + vj.w * vj.w;
  float dpj = vj.x * wj.x + vj.y * wj.y + vj.z * wj.z + vj.w * wj.w;
#pragma unroll
  for (int o = 32; o; o >>= 1) {
    ssi += __shfl_down(ssi, o);
    dpi += __shfl_down(dpi, o);
    ssj += __shfl_down(ssj, o);
    dpj += __shfl_down(dpj, o);
  }
  if (l == 0) {
    out[s] = dpi / fmaxf(sqrtf(ssi), 1e-12f) +
             dpj / fmaxf(sqrtf(ssj), 1e-12f) + b_out[0];
  }
}

extern "C" void kernel_launch(void* const* d_in, const int* in_sizes, int n_in,
                              void* d_out, int out_size, void* d_ws,
                              size_t ws_size, hipStream_t stream) {
  (void)in_sizes; (void)n_in; (void)out_size; (void)ws_size;
  const float* x_i = (const float*)d_in[0];
  const float* x_j = (const float*)d_in[1];
  const int* src_i = (const int*)d_in[2];
  const int* dst_i = (const int*)d_in[3];
  const int* src_j = (const int*)d_in[4];
  const int* dst_j = (const int*)d_in[5];
  const int* ids_i = (const int*)d_in[6];
  const int* ids_j = (const int*)d_in[7];
  const float* Wn1 = (const float*)d_in[8];
  const float* Ws1 = (const float*)d_in[9];
  const float* b1 = (const float*)d_in[10];
  const float* Wn2 = (const float*)d_in[11];
  const float* Ws2 = (const float*)d_in[12];
  const float* b2 = (const float*)d_in[13];
  const float* W_out = (const float*)d_in[14];
  const float* b_out = (const float*)d_in[15];
  float* out = (float*)d_out;

  char* w = (char*)d_ws;
  int* cnt2       = (int*)(w + 0);           // 2*NPAD*4 = 401,408
  int* row_start2 = (int*)(w + 401408);      // 401,408
  int* cursor2    = (int*)(w + 802816);      // 401,408
  int* bsum       = (int*)(w + 1204224);     // 2,048
  int* csr_src2   = (int*)(w + 1206272);     // 6,400,000
  ushort* Wt      = (ushort*)(w + 7606272);  // 131,072
  ushort* W2hi    = (ushort*)(w + 7737344);  // 262,144
  ushort* W2lo    = (ushort*)(w + 7999488);  // 262,144
  ushort* xb2     = (ushort*)(w + 8261632);  // 25,600,000
  ushort* aggb2   = (ushort*)(w + 33861632); // 25,600,000
  ushort* h1b2    = (ushort*)(w + 59461632); // 51,200,000 -> end 110,661,632
  // aliased into xb2/aggb2 region (dead after k_gemm1):
  ushort* A2      = (ushort*)(w + 8261632);  // 16,777,216 -> ends 25,038,848
  float* h2       = (float*)(w + 25038848);  // 16,777,216 -> ends 41,816,064

  k_wt<<<256, 256, 0, stream>>>(Wn1, Ws1, Wt);
  k_w2<<<512, 256, 0, stream>>>(Wn2, Ws2, W2hi, W2lo);
  hipMemsetAsync(cnt2, 0, 2 * NPAD * sizeof(int), stream);
  k_count<<<1563, 256, 0, stream>>>(dst_i, dst_j, cnt2);
  k_scanA<<<392, 256, 0, stream>>>(cnt2, row_start2, bsum);
  k_scanB<<<2, 256, 0, stream>>>(bsum);
  k_scanC<<<392, 256, 0, stream>>>(row_start2, bsum, cursor2);
  k_fill<<<1563, 256, 0, stream>>>(src_i, dst_i, src_j, dst_j, cursor2,
                                   csr_src2);
  k_tobf16<<<12500, 256, 0, stream>>>(x_i, x_j, xb2);
  k_agg1<<<25000, 256, 0, stream>>>(xb2, csr_src2, row_start2, cnt2, aggb2);
  k_gemm1<<<dim3(784, 2), 256, 0, stream>>>(aggb2, xb2, Wt, b1, h1b2);
  k_agg2<<<2 * BS, 256, 0, stream>>>(h1b2, csr_src2, row_start2, cnt2, ids_i,
                                     ids_j, A2);
  k_head<<<dim3(256, 2), 256, 0, stream>>>(A2, W2hi, W2lo, b2, h2);
  k_out<<<2048, 256, 0, stream>>>(h2, W_out, b_out, out);
}

// Round 7
// 261.397 us; speedup vs baseline: 8.1595x; 1.6012x over previous
//
#include <hip/hip_runtime.h>

constexpr int NN = 50000;     // nodes per graph
constexpr int NE = 800000;    // edges per graph
constexpr int IND = 128;      // in dim
constexpr int HD = 256;       // hidden
constexpr int BS = 8192;      // seeds per graph
constexpr int NPAD = 50176;   // 196*256, block-aligned padded node count
constexpr int NBKT = 196;     // dst>>8 buckets per graph
constexpr int BCAP = 8192;    // capacity per bucket (mean 4096, sigma 64)

typedef __attribute__((ext_vector_type(8))) short short8v;
typedef __attribute__((ext_vector_type(4))) float floatx4;

__device__ inline ushort f2b(float f) {  // f32 -> bf16 RNE
  unsigned u = __float_as_uint(f);
  unsigned r = (u + 0x7fffu + ((u >> 16) & 1u)) >> 16;
  return (ushort)r;
}
__device__ inline float b2f(ushort b) {
  return __uint_as_float((unsigned)b << 16);
}
__device__ inline int wave_incl_scan(int x, int lane) {
#pragma unroll
  for (int d = 1; d < 64; d <<= 1) {
    int y = __shfl_up(x, d);
    if (lane >= d) x += y;
  }
  return x;
}

// ---------------- stage 1: bin edges by dst>>8 (LDS multi-split) ----------------
// 196 blocks: 98 per graph, 8192 edges each
__global__ __launch_bounds__(256) void k_bin(const int* __restrict__ src_i,
                                             const int* __restrict__ dst_i,
                                             const int* __restrict__ src_j,
                                             const int* __restrict__ dst_j,
                                             int* __restrict__ bcnt,
                                             int* __restrict__ bucketbuf) {
  __shared__ int hist[NBKT], gbase[NBKT], lcur[NBKT];
  const int blk = blockIdx.x;
  const int g = blk >= 98;
  const int c = blk - g * 98;
  const int* src = g ? src_j : src_i;
  const int* dst = g ? dst_j : dst_i;
  const int t = threadIdx.x;
  if (t < NBKT) hist[t] = 0;
  __syncthreads();
  const int e0 = c * 8192;
#pragma unroll
  for (int k = 0; k < 32; ++k) {
    int e = e0 + k * 256 + t;
    if (e < NE) atomicAdd(&hist[dst[e] >> 8], 1);
  }
  __syncthreads();
  if (t < NBKT) {
    int h = hist[t];
    gbase[t] = h ? atomicAdd(&bcnt[g * NBKT + t], h) : 0;
    lcur[t] = 0;
  }
  __syncthreads();
#pragma unroll
  for (int k = 0; k < 32; ++k) {
    int e = e0 + k * 256 + t;
    if (e < NE) {
      int d = dst[e];
      int b = d >> 8;
      int p = gbase[b] + atomicAdd(&lcur[b], 1);
      if (p < BCAP)
        bucketbuf[(g * NBKT + b) * BCAP + p] = (src[e] << 8) | (d & 255);
    }
  }
}

// ---------------- stage 2a: exclusive scan of 392 bucket totals ----------------
__global__ __launch_bounds__(256) void k_bktscan(const int* __restrict__ bcnt,
                                                 int* __restrict__ bktbase) {
  __shared__ int wt[4];
  __shared__ int carry, tot;
  const int t = threadIdx.x, lane = t & 63;
  if (t == 0) carry = 0;
  __syncthreads();
  for (int ch = 0; ch < 2; ++ch) {
    int i = ch * 256 + t;
    int v = (i < 2 * NBKT) ? min(bcnt[i], BCAP) : 0;
    int x = wave_incl_scan(v, lane);
    if (lane == 63) wt[t >> 6] = x;
    __syncthreads();
    if (t == 0) {
      int run = 0;
#pragma unroll
      for (int j = 0; j < 4; ++j) { int tv = wt[j]; wt[j] = run; run += tv; }
      tot = run;
    }
    __syncthreads();
    if (i < 2 * NBKT) bktbase[i] = carry + x - v + wt[t >> 6];
    __syncthreads();
    if (t == 0) carry += tot;
    __syncthreads();
  }
}

// ---------------- stage 2b: per-bucket CSR build in LDS, coalesced out --------
// 392 blocks, one per bucket
__global__ __launch_bounds__(256) void k_build(const int* __restrict__ bucketbuf,
                                               const int* __restrict__ bcnt,
                                               const int* __restrict__ bktbase,
                                               int* __restrict__ csr,
                                               int* __restrict__ cnt2,
                                               int* __restrict__ row_start2) {
  __shared__ int hist[256], lstart[256], lcur[256];
  __shared__ int stage[BCAP];
  __shared__ int wt[4];
  const int b = blockIdx.x;
  const int g = b >= NBKT;
  const int bb = b - g * NBKT;
  const int t = threadIdx.x, lane = t & 63;
  const int C = min(bcnt[b], BCAP);
  const int base = bktbase[b];
  const int* buf = bucketbuf + b * BCAP;
  hist[t] = 0;
  __syncthreads();
  for (int i = t; i < C; i += 256) atomicAdd(&hist[buf[i] & 255], 1);
  __syncthreads();
  int v = hist[t];
  int x = wave_incl_scan(v, lane);
  if (lane == 63) wt[t >> 6] = x;
  __syncthreads();
  if (t == 0) {
    int run = 0;
#pragma unroll
    for (int j = 0; j < 4; ++j) { int tv = wt[j]; wt[j] = run; run += tv; }
  }
  __syncthreads();
  int ls = x - v + wt[t >> 6];
  lstart[t] = ls;
  lcur[t] = ls;
  __syncthreads();
  for (int i = t; i < C; i += 256) {
    int val = buf[i];
    int p = atomicAdd(&lcur[val & 255], 1);
    stage[p] = val >> 8;
  }
  __syncthreads();
  for (int i = t; i < C; i += 256) csr[base + i] = stage[i];
  int node = bb * 256 + t;  // < NPAD always
  cnt2[g * NPAD + node] = v;
  row_start2[g * NPAD + node] = base + ls;
}

// ---------------- f32 -> bf16 convert, both graphs ----------------
__global__ __launch_bounds__(256) void k_tobf16(const float* __restrict__ x_i,
                                                const float* __restrict__ x_j,
                                                ushort* __restrict__ xb2) {
  int i = blockIdx.x * 256 + threadIdx.x;  // < 3.2M
  int e4 = i * 4;
  int g = e4 >= NN * IND;
  const float* xp = g ? x_j : x_i;
  float4 v = *(const float4*)(xp + (e4 - g * NN * IND));
  ushort4 u;
  u.x = f2b(v.x); u.y = f2b(v.y); u.z = f2b(v.z); u.w = f2b(v.w);
  *(ushort4*)(xb2 + e4) = u;
}

// ---------------- layer-1 weights: Wt[n][k] bf16, k<128->Wn1 ----------------
__global__ __launch_bounds__(256) void k_wt(const float* __restrict__ Wn1,
                                            const float* __restrict__ Ws1,
                                            ushort* __restrict__ Wt) {
  int i = blockIdx.x * 256 + threadIdx.x;  // 65536
  int n = i >> 8, k = i & 255;
  float v = (k < 128) ? Wn1[k * HD + n] : Ws1[(k - 128) * HD + n];
  Wt[n * 256 + k] = f2b(v);
}

// ---------------- layer-2 weights: W2[n][k] split hi/lo, k<256->Wn2 ----------
__global__ __launch_bounds__(256) void k_w2(const float* __restrict__ Wn2,
                                            const float* __restrict__ Ws2,
                                            ushort* __restrict__ Whi,
                                            ushort* __restrict__ Wlo) {
  int i = blockIdx.x * 256 + threadIdx.x;  // 131072
  int n = i >> 9, k = i & 511;
  float v = (k < 256) ? Wn2[k * HD + n] : Ws2[(k - 256) * HD + n];
  ushort hi = f2b(v);
  Whi[n * 512 + k] = hi;
  Wlo[n * 512 + k] = f2b(v - b2f(hi));
}

// ---------------- layer-1 pull aggregation from bf16 (ILP-4) ----------------
__global__ __launch_bounds__(256) void k_agg1(const ushort* __restrict__ xb2,
                                              const int* __restrict__ csr,
                                              const int* __restrict__ row_start2,
                                              const int* __restrict__ cnt2,
                                              ushort* __restrict__ aggb2) {
  int w = threadIdx.x >> 6, l = threadIdx.x & 63;
  int n = blockIdx.x * 4 + w;  // < 2*NN exactly
  int g = n >= NN;
  int nl = n - g * NN;
  int st = row_start2[g * NPAD + nl], deg = cnt2[g * NPAD + nl];
  const ushort* xb = xb2 + g * NN * IND;
  float a0 = 0.f, a1 = 0.f;
  int e = 0;
  for (; e + 4 <= deg; e += 4) {
    int s0 = csr[st + e + 0], s1 = csr[st + e + 1];
    int s2 = csr[st + e + 2], s3 = csr[st + e + 3];
    ushort2 u0 = *(const ushort2*)(xb + s0 * IND + 2 * l);
    ushort2 u1 = *(const ushort2*)(xb + s1 * IND + 2 * l);
    ushort2 u2 = *(const ushort2*)(xb + s2 * IND + 2 * l);
    ushort2 u3 = *(const ushort2*)(xb + s3 * IND + 2 * l);
    a0 += b2f(u0.x) + b2f(u1.x) + b2f(u2.x) + b2f(u3.x);
    a1 += b2f(u0.y) + b2f(u1.y) + b2f(u2.y) + b2f(u3.y);
  }
  for (; e < deg; ++e) {
    int s = csr[st + e];
    ushort2 u = *(const ushort2*)(xb + s * IND + 2 * l);
    a0 += b2f(u.x);
    a1 += b2f(u.y);
  }
  float inv = 1.f / (float)max(deg, 1);
  ushort2 u;
  u.x = f2b(a0 * inv);
  u.y = f2b(a1 * inv);
  *(ushort2*)(aggb2 + (g * NN + nl) * IND + 2 * l) = u;
}

// ---------------- layer-1 MFMA GEMM: h1b = relu([agg|x] @ [Wn1;Ws1] + b1) ----
// grid.x = 784 (392/graph incl. pad block), grid.y = 2 (col halves)
__global__ __launch_bounds__(256) void k_gemm1(const ushort* __restrict__ aggb2,
                                               const ushort* __restrict__ xb2,
                                               const ushort* __restrict__ Wt,
                                               const float* __restrict__ b1,
                                               ushort* __restrict__ h1b2) {
  __shared__ ushort Al[128 * 32];
  __shared__ ushort Bl[128 * 32];
  const int t = threadIdx.x;
  const int g = blockIdx.x >= 392;
  const int row0 = (blockIdx.x - g * 392) * 128, col0 = blockIdx.y * 128;
  const ushort* aggb = aggb2 + g * NN * IND;
  const ushort* xb = xb2 + g * NN * IND;
  ushort* h1b = h1b2 + g * NN * HD;
  const int w = t >> 6, l = t & 63;
  const int wm = w & 1, wn = w >> 1;
  floatx4 acc[4][4];
#pragma unroll
  for (int i = 0; i < 4; ++i)
#pragma unroll
    for (int j = 0; j < 4; ++j) acc[i][j] = (floatx4){0.f, 0.f, 0.f, 0.f};

  for (int kk = 0; kk < 256; kk += 32) {
    const ushort* Abase = (kk < 128) ? (aggb + kk) : (xb + (kk - 128));
#pragma unroll
    for (int s = t; s < 512; s += 256) {
      int r = s >> 2, c = s & 3;
      int grow = row0 + r;
      short8v v = {0, 0, 0, 0, 0, 0, 0, 0};
      if (grow < NN) v = *(const short8v*)(Abase + grow * IND + c * 8);
      *(short8v*)(Al + r * 32 + ((c ^ (r & 3)) * 8)) = v;
    }
#pragma unroll
    for (int s = t; s < 512; s += 256) {
      int r = s >> 2, c = s & 3;
      short8v v = *(const short8v*)(Wt + (col0 + r) * 256 + kk + c * 8);
      *(short8v*)(Bl + r * 32 + ((c ^ (r & 3)) * 8)) = v;
    }
    __syncthreads();
    const int rA = l & 15, gg = l >> 4;
    short8v af[4], bf[4];
#pragma unroll
    for (int i = 0; i < 4; ++i) {
      int r = wm * 64 + i * 16 + rA;
      af[i] = *(const short8v*)(Al + r * 32 + ((gg ^ (r & 3)) * 8));
    }
#pragma unroll
    for (int j = 0; j < 4; ++j) {
      int r = wn * 64 + j * 16 + rA;
      bf[j] = *(const short8v*)(Bl + r * 32 + ((gg ^ (r & 3)) * 8));
    }
#pragma unroll
    for (int i = 0; i < 4; ++i)
#pragma unroll
      for (int j = 0; j < 4; ++j)
        acc[i][j] = __builtin_amdgcn_mfma_f32_16x16x32_bf16(af[i], bf[j],
                                                            acc[i][j], 0, 0, 0);
    __syncthreads();
  }
  const int rD = l >> 4, cD = l & 15;
#pragma unroll
  for (int j = 0; j < 4; ++j) {
    int col = col0 + wn * 64 + j * 16 + cD;
    float bias = b1[col];
#pragma unroll
    for (int i = 0; i < 4; ++i) {
      int rbase = row0 + wm * 64 + i * 16 + rD * 4;
#pragma unroll
      for (int rr = 0; rr < 4; ++rr) {
        int row = rbase + rr;
        if (row < NN)
          h1b[row * HD + col] = f2b(fmaxf(acc[i][j][rr] + bias, 0.f));
      }
    }
  }
}

// ---------------- layer-2 aggregation @ seeds -> compact bf16 A --------------
__global__ __launch_bounds__(256) void k_agg2(
    const ushort* __restrict__ h1b2, const int* __restrict__ csr,
    const int* __restrict__ row_start2, const int* __restrict__ cnt2,
    const int* __restrict__ ids_i, const int* __restrict__ ids_j,
    ushort* __restrict__ A2) {
  __shared__ float red[4][HD];
  const int b = blockIdx.x;
  const int g = b >= BS;
  const int node = (g ? ids_j : ids_i)[b - g * BS];
  const int st = row_start2[g * NPAD + node], deg = cnt2[g * NPAD + node];
  const ushort* h1b = h1b2 + g * NN * HD;
  const int w = threadIdx.x >> 6, l = threadIdx.x & 63;
  float a0 = 0.f, a1 = 0.f, a2 = 0.f, a3 = 0.f;
  for (int e = w; e < deg; e += 4) {
    int s = csr[st + e];
    ushort4 u = *(const ushort4*)(h1b + s * HD + l * 4);
    a0 += b2f(u.x); a1 += b2f(u.y); a2 += b2f(u.z); a3 += b2f(u.w);
  }
  red[w][l * 4 + 0] = a0;
  red[w][l * 4 + 1] = a1;
  red[w][l * 4 + 2] = a2;
  red[w][l * 4 + 3] = a3;
  __syncthreads();
  const int t = threadIdx.x;
  float s = (red[0][t] + red[1][t]) + (red[2][t] + red[3][t]);
  s *= 1.f / (float)max(deg, 1);
  A2[b * 512 + t] = f2b(s);
  A2[b * 512 + 256 + t] = h1b[node * HD + t];  // exact bf16 copy
}

// ---------------- layer-2 MFMA GEMM: h2 = A @ [Whi+Wlo] + b2 ----------------
__global__ __launch_bounds__(256) void k_head(const ushort* __restrict__ A2,
                                              const ushort* __restrict__ Whi,
                                              const ushort* __restrict__ Wlo,
                                              const float* __restrict__ b2,
                                              float* __restrict__ h2) {
  __shared__ ushort Ahl[64 * 32];
  __shared__ ushort Bhl[128 * 32];
  __shared__ ushort Bll[128 * 32];
  const int t = threadIdx.x;
  const int row0 = blockIdx.x * 64, col0 = blockIdx.y * 128;
  const int w = t >> 6, l = t & 63;
  const int wm = w & 1, wn = w >> 1;
  floatx4 acc[2][4];
#pragma unroll
  for (int i = 0; i < 2; ++i)
#pragma unroll
    for (int j = 0; j < 4; ++j) acc[i][j] = (floatx4){0.f, 0.f, 0.f, 0.f};

  for (int kk = 0; kk < 512; kk += 32) {
    if (t < 256) {
      int r = t >> 2, c = t & 3;
      int sw = (c ^ (r & 3)) * 8;
      *(short8v*)(Ahl + r * 32 + sw) =
          *(const short8v*)(A2 + (row0 + r) * 512 + kk + c * 8);
    }
#pragma unroll
    for (int s = t; s < 512; s += 256) {
      int r = s >> 2, c = s & 3;
      int sw = (c ^ (r & 3)) * 8;
      *(short8v*)(Bhl + r * 32 + sw) =
          *(const short8v*)(Whi + (col0 + r) * 512 + kk + c * 8);
      *(short8v*)(Bll + r * 32 + sw) =
          *(const short8v*)(Wlo + (col0 + r) * 512 + kk + c * 8);
    }
    __syncthreads();
    const int rA = l & 15, gg = l >> 4;
    short8v ah[2], bh[4], bl[4];
#pragma unroll
    for (int i = 0; i < 2; ++i) {
      int r = wm * 32 + i * 16 + rA;
      ah[i] = *(const short8v*)(Ahl + r * 32 + ((gg ^ (r & 3)) * 8));
    }
#pragma unroll
    for (int j = 0; j < 4; ++j) {
      int r = wn * 64 + j * 16 + rA;
      int sw = (gg ^ (r & 3)) * 8;
      bh[j] = *(const short8v*)(Bhl + r * 32 + sw);
      bl[j] = *(const short8v*)(Bll + r * 32 + sw);
    }
#pragma unroll
    for (int i = 0; i < 2; ++i)
#pragma unroll
      for (int j = 0; j < 4; ++j) {
        acc[i][j] = __builtin_amdgcn_mfma_f32_16x16x32_bf16(ah[i], bh[j],
                                                            acc[i][j], 0, 0, 0);
        acc[i][j] = __builtin_amdgcn_mfma_f32_16x16x32_bf16(ah[i], bl[j],
                                                            acc[i][j], 0, 0, 0);
      }
    __syncthreads();
  }
  const int rD = l >> 4, cD = l & 15;
#pragma unroll
  for (int j = 0; j < 4; ++j) {
    int col = col0 + wn * 64 + j * 16 + cD;
    float bias = b2[col];
#pragma unroll
    for (int i = 0; i < 2; ++i) {
      int rbase = row0 + wm * 32 + i * 16 + rD * 4;
#pragma unroll
      for (int rr = 0; rr < 4; ++rr) {
        h2[(rbase + rr) * HD + col] = acc[i][j][rr] + bias;
      }
    }
  }
}

// ---------------- l2norm + head dot (both halves fused) ----------------
__global__ __launch_bounds__(256) void k_out(const float* __restrict__ h2,
                                             const float* __restrict__ W_out,
                                             const float* __restrict__ b_out,
                                             float* __restrict__ out) {
  int w = threadIdx.x >> 6, l = threadIdx.x & 63;
  int s = blockIdx.x * 4 + w;  // seed, < 8192
  float4 vi = *(const float4*)(h2 + s * HD + l * 4);
  float4 vj = *(const float4*)(h2 + (s + BS) * HD + l * 4);
  float4 wi = *(const float4*)(W_out + l * 4);
  float4 wj = *(const float4*)(W_out + 256 + l * 4);
  float ssi = vi.x * vi.x + vi.y * vi.y + vi.z * vi.z + vi.w * vi.w;
  float dpi = vi.x * wi.x + vi.y * wi.y + vi.z * wi.z + vi.w * wi.w;
  float ssj = vj.x * vj.x + vj.y * vj.y + vj.z * vj.z + vj.w * vj.w;
  float dpj = vj.x * wj.x + vj.y * wj.y + vj.z * wj.z + vj.w * wj.w;
#pragma unroll
  for (int o = 32; o; o >>= 1) {
    ssi += __shfl_down(ssi, o);
    dpi += __shfl_down(dpi, o);
    ssj += __shfl_down(ssj, o);
    dpj += __shfl_down(dpj, o);
  }
  if (l == 0) {
    out[s] = dpi / fmaxf(sqrtf(ssi), 1e-12f) +
             dpj / fmaxf(sqrtf(ssj), 1e-12f) + b_out[0];
  }
}

extern "C" void kernel_launch(void* const* d_in, const int* in_sizes, int n_in,
                              void* d_out, int out_size, void* d_ws,
                              size_t ws_size, hipStream_t stream) {
  (void)in_sizes; (void)n_in; (void)out_size; (void)ws_size;
  const float* x_i = (const float*)d_in[0];
  const float* x_j = (const float*)d_in[1];
  const int* src_i = (const int*)d_in[2];
  const int* dst_i = (const int*)d_in[3];
  const int* src_j = (const int*)d_in[4];
  const int* dst_j = (const int*)d_in[5];
  const int* ids_i = (const int*)d_in[6];
  const int* ids_j = (const int*)d_in[7];
  const float* Wn1 = (const float*)d_in[8];
  const float* Ws1 = (const float*)d_in[9];
  const float* b1 = (const float*)d_in[10];
  const float* Wn2 = (const float*)d_in[11];
  const float* Ws2 = (const float*)d_in[12];
  const float* b2 = (const float*)d_in[13];
  const float* W_out = (const float*)d_in[14];
  const float* b_out = (const float*)d_in[15];
  float* out = (float*)d_out;

  char* w = (char*)d_ws;
  int* bcnt       = (int*)(w + 0);            // 1,568
  int* bktbase    = (int*)(w + 2048);         // 1,568
  int* cnt2       = (int*)(w + 4096);         // 401,408
  int* row_start2 = (int*)(w + 405504);       // 401,408
  int* bucketbuf  = (int*)(w + 806912);       // 12,845,056 -> 13,651,968
  ushort* Wt      = (ushort*)(w + 13651968);  // 131,072
  ushort* W2hi    = (ushort*)(w + 13783040);  // 262,144
  ushort* W2lo    = (ushort*)(w + 14045184);  // 262,144
  ushort* xb2     = (ushort*)(w + 14307328);  // 25,600,000 -> 39,907,328
  ushort* aggb2   = (ushort*)(w + 39907328);  // 25,600,000 -> 65,507,328
  ushort* h1b2    = (ushort*)(w + 65507328);  // 51,200,000 -> 116,707,328
  int* csr        = (int*)(w + 116707328);    // 6,400,000 -> 123,107,328
  // aliases over xb2/aggb2 (dead after k_gemm1):
  ushort* A2      = (ushort*)(w + 14307328);  // 16,777,216 -> 31,084,544
  float* h2       = (float*)(w + 31084544);   // 16,777,216 -> 47,861,760

  k_wt<<<256, 256, 0, stream>>>(Wn1, Ws1, Wt);
  k_w2<<<512, 256, 0, stream>>>(Wn2, Ws2, W2hi, W2lo);
  hipMemsetAsync(bcnt, 0, 2 * NBKT * sizeof(int), stream);
  k_bin<<<196, 256, 0, stream>>>(src_i, dst_i, src_j, dst_j, bcnt, bucketbuf);
  k_bktscan<<<1, 256, 0, stream>>>(bcnt, bktbase);
  k_build<<<392, 256, 0, stream>>>(bucketbuf, bcnt, bktbase, csr, cnt2,
                                   row_start2);
  k_tobf16<<<12500, 256, 0, stream>>>(x_i, x_j, xb2);
  k_agg1<<<25000, 256, 0, stream>>>(xb2, csr, row_start2, cnt2, aggb2);
  k_gemm1<<<dim3(784, 2), 256, 0, stream>>>(aggb2, xb2, Wt, b1, h1b2);
  k_agg2<<<2 * BS, 256, 0, stream>>>(h1b2, csr, row_start2, cnt2, ids_i, ids_j,
                                     A2);
  k_head<<<dim3(256, 2), 256, 0, stream>>>(A2, W2hi, W2lo, b2, h2);
  k_out<<<2048, 256, 0, stream>>>(h2, W_out, b_out, out);
}

// Round 8
// 211.458 us; speedup vs baseline: 10.0865x; 1.2362x over previous
//
#include <hip/hip_runtime.h>

constexpr int NN = 50000;     // nodes per graph
constexpr int NE = 800000;    // edges per graph
constexpr int IND = 128;      // in dim
constexpr int HD = 256;       // hidden
constexpr int BS = 8192;      // seeds per graph
constexpr int NPAD = 50176;   // 196*256, block-aligned padded node count
constexpr int NBKT = 196;     // dst>>8 buckets per graph
constexpr int BCAP = 8192;    // capacity per bucket (mean 4096, sigma 64)

typedef __attribute__((ext_vector_type(8))) short short8v;
typedef __attribute__((ext_vector_type(4))) float floatx4;

__device__ inline ushort f2b(float f) {  // f32 -> bf16 RNE
  unsigned u = __float_as_uint(f);
  unsigned r = (u + 0x7fffu + ((u >> 16) & 1u)) >> 16;
  return (ushort)r;
}
__device__ inline float b2f(ushort b) {
  return __uint_as_float((unsigned)b << 16);
}
// accumulate both bf16 halves of a packed u32 (low elem, high elem)
__device__ __forceinline__ void acc2(unsigned u, float& a0, float& a1) {
  a0 += __uint_as_float(u << 16);
  a1 += __uint_as_float(u & 0xffff0000u);
}
__device__ inline int wave_incl_scan(int x, int lane) {
#pragma unroll
  for (int d = 1; d < 64; d <<= 1) {
    int y = __shfl_up(x, d);
    if (lane >= d) x += y;
  }
  return x;
}

// async global->LDS, 16B per lane, wave-uniform LDS base
__device__ __forceinline__ void gload16(const ushort* g, ushort* l) {
  __builtin_amdgcn_global_load_lds(
      (const __attribute__((address_space(1))) void*)g,
      (__attribute__((address_space(3))) void*)l, 16, 0, 0);
}

// ---------------- stage 1: bin edges by dst>>8 (LDS multi-split) ----------------
__global__ __launch_bounds__(256) void k_bin(const int* __restrict__ src_i,
                                             const int* __restrict__ dst_i,
                                             const int* __restrict__ src_j,
                                             const int* __restrict__ dst_j,
                                             int* __restrict__ bcnt,
                                             int* __restrict__ bucketbuf) {
  __shared__ int hist[NBKT], gbase[NBKT], lcur[NBKT];
  const int blk = blockIdx.x;
  const int g = blk >= 98;
  const int c = blk - g * 98;
  const int* src = g ? src_j : src_i;
  const int* dst = g ? dst_j : dst_i;
  const int t = threadIdx.x;
  if (t < NBKT) hist[t] = 0;
  __syncthreads();
  const int e0 = c * 8192;
#pragma unroll
  for (int k = 0; k < 32; ++k) {
    int e = e0 + k * 256 + t;
    if (e < NE) atomicAdd(&hist[dst[e] >> 8], 1);
  }
  __syncthreads();
  if (t < NBKT) {
    int h = hist[t];
    gbase[t] = h ? atomicAdd(&bcnt[g * NBKT + t], h) : 0;
    lcur[t] = 0;
  }
  __syncthreads();
#pragma unroll
  for (int k = 0; k < 32; ++k) {
    int e = e0 + k * 256 + t;
    if (e < NE) {
      int d = dst[e];
      int b = d >> 8;
      int p = gbase[b] + atomicAdd(&lcur[b], 1);
      if (p < BCAP)
        bucketbuf[(g * NBKT + b) * BCAP + p] = (src[e] << 8) | (d & 255);
    }
  }
}

// ---------------- stage 2a: exclusive scan of 392 bucket totals ----------------
__global__ __launch_bounds__(256) void k_bktscan(const int* __restrict__ bcnt,
                                                 int* __restrict__ bktbase) {
  __shared__ int wt[4];
  __shared__ int carry, tot;
  const int t = threadIdx.x, lane = t & 63;
  if (t == 0) carry = 0;
  __syncthreads();
  for (int ch = 0; ch < 2; ++ch) {
    int i = ch * 256 + t;
    int v = (i < 2 * NBKT) ? min(bcnt[i], BCAP) : 0;
    int x = wave_incl_scan(v, lane);
    if (lane == 63) wt[t >> 6] = x;
    __syncthreads();
    if (t == 0) {
      int run = 0;
#pragma unroll
      for (int j = 0; j < 4; ++j) { int tv = wt[j]; wt[j] = run; run += tv; }
      tot = run;
    }
    __syncthreads();
    if (i < 2 * NBKT) bktbase[i] = carry + x - v + wt[t >> 6];
    __syncthreads();
    if (t == 0) carry += tot;
    __syncthreads();
  }
}

// ---------------- stage 2b: per-bucket CSR build in LDS, coalesced out --------
__global__ __launch_bounds__(256) void k_build(const int* __restrict__ bucketbuf,
                                               const int* __restrict__ bcnt,
                                               const int* __restrict__ bktbase,
                                               int* __restrict__ csr,
                                               int* __restrict__ cnt2,
                                               int* __restrict__ row_start2) {
  __shared__ int hist[256], lstart[256], lcur[256];
  __shared__ int stage[BCAP];
  __shared__ int wt[4];
  const int b = blockIdx.x;
  const int g = b >= NBKT;
  const int bb = b - g * NBKT;
  const int t = threadIdx.x, lane = t & 63;
  const int C = min(bcnt[b], BCAP);
  const int base = bktbase[b];
  const int* buf = bucketbuf + b * BCAP;
  hist[t] = 0;
  __syncthreads();
  for (int i = t; i < C; i += 256) atomicAdd(&hist[buf[i] & 255], 1);
  __syncthreads();
  int v = hist[t];
  int x = wave_incl_scan(v, lane);
  if (lane == 63) wt[t >> 6] = x;
  __syncthreads();
  if (t == 0) {
    int run = 0;
#pragma unroll
    for (int j = 0; j < 4; ++j) { int tv = wt[j]; wt[j] = run; run += tv; }
  }
  __syncthreads();
  int ls = x - v + wt[t >> 6];
  lstart[t] = ls;
  lcur[t] = ls;
  __syncthreads();
  for (int i = t; i < C; i += 256) {
    int val = buf[i];
    int p = atomicAdd(&lcur[val & 255], 1);
    stage[p] = val >> 8;
  }
  __syncthreads();
  for (int i = t; i < C; i += 256) csr[base + i] = stage[i];
  int node = bb * 256 + t;
  cnt2[g * NPAD + node] = v;
  row_start2[g * NPAD + node] = base + ls;
}

// ---------------- f32 -> bf16 convert, both graphs ----------------
__global__ __launch_bounds__(256) void k_tobf16(const float* __restrict__ x_i,
                                                const float* __restrict__ x_j,
                                                ushort* __restrict__ xb2) {
  int i = blockIdx.x * 256 + threadIdx.x;
  int e4 = i * 4;
  int g = e4 >= NN * IND;
  const float* xp = g ? x_j : x_i;
  float4 v = *(const float4*)(xp + (e4 - g * NN * IND));
  ushort4 u;
  u.x = f2b(v.x); u.y = f2b(v.y); u.z = f2b(v.z); u.w = f2b(v.w);
  *(ushort4*)(xb2 + e4) = u;
}

// ---------------- layer-1 weights: Wt[n][k] bf16, k<128->Wn1 ----------------
__global__ __launch_bounds__(256) void k_wt(const float* __restrict__ Wn1,
                                            const float* __restrict__ Ws1,
                                            ushort* __restrict__ Wt) {
  int i = blockIdx.x * 256 + threadIdx.x;
  int n = i >> 8, k = i & 255;
  float v = (k < 128) ? Wn1[k * HD + n] : Ws1[(k - 128) * HD + n];
  Wt[n * 256 + k] = f2b(v);
}

// ---------------- layer-2 weights: W2[n][k] split hi/lo, k<256->Wn2 ----------
__global__ __launch_bounds__(256) void k_w2(const float* __restrict__ Wn2,
                                            const float* __restrict__ Ws2,
                                            ushort* __restrict__ Whi,
                                            ushort* __restrict__ Wlo) {
  int i = blockIdx.x * 256 + threadIdx.x;
  int n = i >> 9, k = i & 511;
  float v = (k < 256) ? Wn2[k * HD + n] : Ws2[(k - 256) * HD + n];
  ushort hi = f2b(v);
  Whi[n * 512 + k] = hi;
  Wlo[n * 512 + k] = f2b(v - b2f(hi));
}

// ---------------- layer-1 pull aggregation from bf16 (ILP-8) ----------------
__global__ __launch_bounds__(256) void k_agg1(const ushort* __restrict__ xb2,
                                              const int* __restrict__ csr,
                                              const int* __restrict__ row_start2,
                                              const int* __restrict__ cnt2,
                                              ushort* __restrict__ aggb2) {
  int w = threadIdx.x >> 6, l = threadIdx.x & 63;
  int n = blockIdx.x * 4 + w;
  int g = n >= NN;
  int nl = n - g * NN;
  int st = row_start2[g * NPAD + nl], deg = cnt2[g * NPAD + nl];
  const ushort* xb = xb2 + g * NN * IND;
  float a0 = 0.f, a1 = 0.f;
  int e = 0;
  for (; e + 8 <= deg; e += 8) {
    int s0 = csr[st + e + 0], s1 = csr[st + e + 1];
    int s2 = csr[st + e + 2], s3 = csr[st + e + 3];
    int s4 = csr[st + e + 4], s5 = csr[st + e + 5];
    int s6 = csr[st + e + 6], s7 = csr[st + e + 7];
    unsigned u0 = *(const unsigned*)(xb + s0 * IND + 2 * l);
    unsigned u1 = *(const unsigned*)(xb + s1 * IND + 2 * l);
    unsigned u2 = *(const unsigned*)(xb + s2 * IND + 2 * l);
    unsigned u3 = *(const unsigned*)(xb + s3 * IND + 2 * l);
    unsigned u4 = *(const unsigned*)(xb + s4 * IND + 2 * l);
    unsigned u5 = *(const unsigned*)(xb + s5 * IND + 2 * l);
    unsigned u6 = *(const unsigned*)(xb + s6 * IND + 2 * l);
    unsigned u7 = *(const unsigned*)(xb + s7 * IND + 2 * l);
    acc2(u0, a0, a1); acc2(u1, a0, a1); acc2(u2, a0, a1); acc2(u3, a0, a1);
    acc2(u4, a0, a1); acc2(u5, a0, a1); acc2(u6, a0, a1); acc2(u7, a0, a1);
  }
  for (; e + 4 <= deg; e += 4) {
    int s0 = csr[st + e + 0], s1 = csr[st + e + 1];
    int s2 = csr[st + e + 2], s3 = csr[st + e + 3];
    unsigned u0 = *(const unsigned*)(xb + s0 * IND + 2 * l);
    unsigned u1 = *(const unsigned*)(xb + s1 * IND + 2 * l);
    unsigned u2 = *(const unsigned*)(xb + s2 * IND + 2 * l);
    unsigned u3 = *(const unsigned*)(xb + s3 * IND + 2 * l);
    acc2(u0, a0, a1); acc2(u1, a0, a1); acc2(u2, a0, a1); acc2(u3, a0, a1);
  }
  for (; e < deg; ++e) {
    int s = csr[st + e];
    unsigned u = *(const unsigned*)(xb + s * IND + 2 * l);
    acc2(u, a0, a1);
  }
  float inv = 1.f / (float)max(deg, 1);
  ushort2 u;
  u.x = f2b(a0 * inv);
  u.y = f2b(a1 * inv);
  *(ushort2*)(aggb2 + (g * NN + nl) * IND + 2 * l) = u;
}

// ---------------- layer-1 MFMA GEMM: h1b = relu([agg|x] @ [Wn1;Ws1] + b1) ----
// global_load_lds double-buffered; pre-swizzled source, swizzled ds_read;
// LDS-staged coalesced bf16 epilogue. grid (784, 2).
__global__ __launch_bounds__(256) void k_gemm1(const ushort* __restrict__ aggb2,
                                               const ushort* __restrict__ xb2,
                                               const ushort* __restrict__ Wt,
                                               const float* __restrict__ b1,
                                               ushort* __restrict__ h1b2) {
  __shared__ ushort smem[16384];  // A dbuf [2][4096] | B dbuf [2][4096]; epilogue: C[128][128]
  const int t = threadIdx.x;
  const int g = blockIdx.x >= 392;
  const int row0 = (blockIdx.x - g * 392) * 128, col0 = blockIdx.y * 128;
  const ushort* aggb = aggb2 + g * NN * IND;
  const ushort* xb = xb2 + g * NN * IND;
  ushort* h1b = h1b2 + g * NN * HD;
  const int w = t >> 6, l = t & 63;
  const int wm = w & 1, wn = w >> 1;

  // staging addresses: chunk s = q*256 + t; r = s>>2, dest slot cs = s&3,
  // source chunk c = cs ^ (r&3)  (XOR involution; read uses same swizzle)
  const int r0 = t >> 2, cs0 = t & 3;
  const int c0 = cs0 ^ (r0 & 3);
  const int rA0 = min(row0 + r0, NN - 1);
  const int rA1 = min(row0 + r0 + 64, NN - 1);
  const int gA0 = rA0 * IND + c0 * 8;
  const int gA1 = rA1 * IND + c0 * 8;
  const int gB0 = (col0 + r0) * 256 + c0 * 8;
  const int gB1 = (col0 + r0 + 64) * 256 + c0 * 8;
  const int wofs = w * 512;  // wave-uniform LDS ushort offset per call

  floatx4 acc[4][4];
#pragma unroll
  for (int i = 0; i < 4; ++i)
#pragma unroll
    for (int j = 0; j < 4; ++j) acc[i][j] = (floatx4){0.f, 0.f, 0.f, 0.f};

#define STAGE(buf, kk)                                                      \
  do {                                                                      \
    const ushort* Ab = ((kk) < 128) ? (aggb + (kk)) : (xb + ((kk) - 128));  \
    ushort* Ald = smem + (buf) * 4096;                                      \
    ushort* Bld = smem + 8192 + (buf) * 4096;                               \
    gload16(Ab + gA0, Ald + wofs);                                          \
    gload16(Ab + gA1, Ald + 2048 + wofs);                                   \
    gload16(Wt + gB0 + (kk), Bld + wofs);                                   \
    gload16(Wt + gB1 + (kk), Bld + 2048 + wofs);                            \
  } while (0)

  STAGE(0, 0);
  __syncthreads();
  int cur = 0;
  const int rA = l & 15, gg = l >> 4;
  for (int step = 0; step < 8; ++step) {
    if (step < 7) STAGE(cur ^ 1, (step + 1) * 32);
    const ushort* Abuf = smem + cur * 4096;
    const ushort* Bbuf = smem + 8192 + cur * 4096;
    short8v af[4], bf[4];
#pragma unroll
    for (int i = 0; i < 4; ++i) {
      int r = wm * 64 + i * 16 + rA;
      af[i] = *(const short8v*)(Abuf + r * 32 + ((gg ^ (r & 3)) * 8));
    }
#pragma unroll
    for (int j = 0; j < 4; ++j) {
      int r = wn * 64 + j * 16 + rA;
      bf[j] = *(const short8v*)(Bbuf + r * 32 + ((gg ^ (r & 3)) * 8));
    }
#pragma unroll
    for (int i = 0; i < 4; ++i)
#pragma unroll
      for (int j = 0; j < 4; ++j)
        acc[i][j] = __builtin_amdgcn_mfma_f32_16x16x32_bf16(af[i], bf[j],
                                                            acc[i][j], 0, 0, 0);
    if (step < 7) {
      __syncthreads();  // drains vmcnt (next stage) + lgkmcnt (our ds_reads)
      cur ^= 1;
    }
  }
#undef STAGE

  // epilogue: acc -> bf16 LDS tile, then coalesced 256B-row stores
  __syncthreads();
  const int rD = l >> 4, cD = l & 15;
#pragma unroll
  for (int j = 0; j < 4; ++j) {
    int cl = wn * 64 + j * 16 + cD;
    float bias = b1[col0 + cl];
#pragma unroll
    for (int i = 0; i < 4; ++i) {
      int rbase = wm * 64 + i * 16 + rD * 4;
#pragma unroll
      for (int rr = 0; rr < 4; ++rr)
        smem[(rbase + rr) * 128 + cl] = f2b(fmaxf(acc[i][j][rr] + bias, 0.f));
    }
  }
  __syncthreads();
  const int rl = t >> 4, ch = t & 15;
#pragma unroll
  for (int it = 0; it < 8; ++it) {
    int row_l = rl + it * 16;
    int grow = row0 + row_l;
    if (grow < NN)
      *(short8v*)(h1b + grow * HD + col0 + ch * 8) =
          *(const short8v*)(smem + row_l * 128 + ch * 8);
  }
}

// ---------------- layer-2 aggregation @ seeds -> compact bf16 A (ILP-2) ------
__global__ __launch_bounds__(256) void k_agg2(
    const ushort* __restrict__ h1b2, const int* __restrict__ csr,
    const int* __restrict__ row_start2, const int* __restrict__ cnt2,
    const int* __restrict__ ids_i, const int* __restrict__ ids_j,
    ushort* __restrict__ A2) {
  __shared__ float red[4][HD];
  const int b = blockIdx.x;
  const int g = b >= BS;
  const int node = (g ? ids_j : ids_i)[b - g * BS];
  const int st = row_start2[g * NPAD + node], deg = cnt2[g * NPAD + node];
  const ushort* h1b = h1b2 + g * NN * HD;
  const int w = threadIdx.x >> 6, l = threadIdx.x & 63;
  float a0 = 0.f, a1 = 0.f, a2 = 0.f, a3 = 0.f;
  int e = w;
  for (; e + 4 < deg; e += 8) {
    int sa = csr[st + e], sb = csr[st + e + 4];
    uint2 ua = *(const uint2*)(h1b + sa * HD + l * 4);
    uint2 ub = *(const uint2*)(h1b + sb * HD + l * 4);
    acc2(ua.x, a0, a1); acc2(ua.y, a2, a3);
    acc2(ub.x, a0, a1); acc2(ub.y, a2, a3);
  }
  if (e < deg) {
    int sa = csr[st + e];
    uint2 ua = *(const uint2*)(h1b + sa * HD + l * 4);
    acc2(ua.x, a0, a1); acc2(ua.y, a2, a3);
  }
  red[w][l * 4 + 0] = a0;
  red[w][l * 4 + 1] = a1;
  red[w][l * 4 + 2] = a2;
  red[w][l * 4 + 3] = a3;
  __syncthreads();
  const int t = threadIdx.x;
  float s = (red[0][t] + red[1][t]) + (red[2][t] + red[3][t]);
  s *= 1.f / (float)max(deg, 1);
  A2[b * 512 + t] = f2b(s);
  A2[b * 512 + 256 + t] = h1b[node * HD + t];  // exact bf16 copy
}

// ---------------- layer-2 MFMA GEMM: h2 = A @ [Whi+Wlo] + b2 ----------------
__global__ __launch_bounds__(256) void k_head(const ushort* __restrict__ A2,
                                              const ushort* __restrict__ Whi,
                                              const ushort* __restrict__ Wlo,
                                              const float* __restrict__ b2,
                                              float* __restrict__ h2) {
  __shared__ ushort Ahl[64 * 32];
  __shared__ ushort Bhl[128 * 32];
  __shared__ ushort Bll[128 * 32];
  const int t = threadIdx.x;
  const int row0 = blockIdx.x * 64, col0 = blockIdx.y * 128;
  const int w = t >> 6, l = t & 63;
  const int wm = w & 1, wn = w >> 1;
  floatx4 acc[2][4];
#pragma unroll
  for (int i = 0; i < 2; ++i)
#pragma unroll
    for (int j = 0; j < 4; ++j) acc[i][j] = (floatx4){0.f, 0.f, 0.f, 0.f};

  for (int kk = 0; kk < 512; kk += 32) {
    if (t < 256) {
      int r = t >> 2, c = t & 3;
      int sw = (c ^ (r & 3)) * 8;
      *(short8v*)(Ahl + r * 32 + sw) =
          *(const short8v*)(A2 + (row0 + r) * 512 + kk + c * 8);
    }
#pragma unroll
    for (int s = t; s < 512; s += 256) {
      int r = s >> 2, c = s & 3;
      int sw = (c ^ (r & 3)) * 8;
      *(short8v*)(Bhl + r * 32 + sw) =
          *(const short8v*)(Whi + (col0 + r) * 512 + kk + c * 8);
      *(short8v*)(Bll + r * 32 + sw) =
          *(const short8v*)(Wlo + (col0 + r) * 512 + kk + c * 8);
    }
    __syncthreads();
    const int rA = l & 15, gg = l >> 4;
    short8v ah[2], bh[4], bl[4];
#pragma unroll
    for (int i = 0; i < 2; ++i) {
      int r = wm * 32 + i * 16 + rA;
      ah[i] = *(const short8v*)(Ahl + r * 32 + ((gg ^ (r & 3)) * 8));
    }
#pragma unroll
    for (int j = 0; j < 4; ++j) {
      int r = wn * 64 + j * 16 + rA;
      int sw = (gg ^ (r & 3)) * 8;
      bh[j] = *(const short8v*)(Bhl + r * 32 + sw);
      bl[j] = *(const short8v*)(Bll + r * 32 + sw);
    }
#pragma unroll
    for (int i = 0; i < 2; ++i)
#pragma unroll
      for (int j = 0; j < 4; ++j) {
        acc[i][j] = __builtin_amdgcn_mfma_f32_16x16x32_bf16(ah[i], bh[j],
                                                            acc[i][j], 0, 0, 0);
        acc[i][j] = __builtin_amdgcn_mfma_f32_16x16x32_bf16(ah[i], bl[j],
                                                            acc[i][j], 0, 0, 0);
      }
    __syncthreads();
  }
  const int rD = l >> 4, cD = l & 15;
#pragma unroll
  for (int j = 0; j < 4; ++j) {
    int col = col0 + wn * 64 + j * 16 + cD;
    float bias = b2[col];
#pragma unroll
    for (int i = 0; i < 2; ++i) {
      int rbase = row0 + wm * 32 + i * 16 + rD * 4;
#pragma unroll
      for (int rr = 0; rr < 4; ++rr) {
        h2[(rbase + rr) * HD + col] = acc[i][j][rr] + bias;
      }
    }
  }
}

// ---------------- l2norm + head dot (both halves fused) ----------------
__global__ __launch_bounds__(256) void k_out(const float* __restrict__ h2,
                                             const float* __restrict__ W_out,
                                             const float* __restrict__ b_out,
                                             float* __restrict__ out) {
  int w = threadIdx.x >> 6, l = threadIdx.x & 63;
  int s = blockIdx.x * 4 + w;
  float4 vi = *(const float4*)(h2 + s * HD + l * 4);
  float4 vj = *(const float4*)(h2 + (s + BS) * HD + l * 4);
  float4 wi = *(const float4*)(W_out + l * 4);
  float4 wj = *(const float4*)(W_out + 256 + l * 4);
  float ssi = vi.x * vi.x + vi.y * vi.y + vi.z * vi.z + vi.w * vi.w;
  float dpi = vi.x * wi.x + vi.y * wi.y + vi.z * wi.z + vi.w * wi.w;
  float ssj = vj.x * vj.x + vj.y * vj.y + vj.z * vj.z + vj.w * vj.w;
  float dpj = vj.x * wj.x + vj.y * wj.y + vj.z * wj.z + vj.w * wj.w;
#pragma unroll
  for (int o = 32; o; o >>= 1) {
    ssi += __shfl_down(ssi, o);
    dpi += __shfl_down(dpi, o);
    ssj += __shfl_down(ssj, o);
    dpj += __shfl_down(dpj, o);
  }
  if (l == 0) {
    out[s] = dpi / fmaxf(sqrtf(ssi), 1e-12f) +
             dpj / fmaxf(sqrtf(ssj), 1e-12f) + b_out[0];
  }
}

extern "C" void kernel_launch(void* const* d_in, const int* in_sizes, int n_in,
                              void* d_out, int out_size, void* d_ws,
                              size_t ws_size, hipStream_t stream) {
  (void)in_sizes; (void)n_in; (void)out_size; (void)ws_size;
  const float* x_i = (const float*)d_in[0];
  const float* x_j = (const float*)d_in[1];
  const int* src_i = (const int*)d_in[2];
  const int* dst_i = (const int*)d_in[3];
  const int* src_j = (const int*)d_in[4];
  const int* dst_j = (const int*)d_in[5];
  const int* ids_i = (const int*)d_in[6];
  const int* ids_j = (const int*)d_in[7];
  const float* Wn1 = (const float*)d_in[8];
  const float* Ws1 = (const float*)d_in[9];
  const float* b1 = (const float*)d_in[10];
  const float* Wn2 = (const float*)d_in[11];
  const float* Ws2 = (const float*)d_in[12];
  const float* b2 = (const float*)d_in[13];
  const float* W_out = (const float*)d_in[14];
  const float* b_out = (const float*)d_in[15];
  float* out = (float*)d_out;

  char* w = (char*)d_ws;
  int* bcnt       = (int*)(w + 0);            // 1,568
  int* bktbase    = (int*)(w + 2048);         // 1,568
  int* cnt2       = (int*)(w + 4096);         // 401,408
  int* row_start2 = (int*)(w + 405504);       // 401,408
  int* bucketbuf  = (int*)(w + 806912);       // 12,845,056 -> 13,651,968
  ushort* Wt      = (ushort*)(w + 13651968);  // 131,072
  ushort* W2hi    = (ushort*)(w + 13783040);  // 262,144
  ushort* W2lo    = (ushort*)(w + 14045184);  // 262,144
  ushort* xb2     = (ushort*)(w + 14307328);  // 25,600,000 -> 39,907,328
  ushort* aggb2   = (ushort*)(w + 39907328);  // 25,600,000 -> 65,507,328
  ushort* h1b2    = (ushort*)(w + 65507328);  // 51,200,000 -> 116,707,328
  int* csr        = (int*)(w + 116707328);    // 6,400,000 -> 123,107,328
  // aliases over xb2/aggb2 (dead after k_gemm1):
  ushort* A2      = (ushort*)(w + 14307328);  // 16,777,216 -> 31,084,544
  float* h2       = (float*)(w + 31084544);   // 16,777,216 -> 47,861,760

  k_wt<<<256, 256, 0, stream>>>(Wn1, Ws1, Wt);
  k_w2<<<512, 256, 0, stream>>>(Wn2, Ws2, W2hi, W2lo);
  hipMemsetAsync(bcnt, 0, 2 * NBKT * sizeof(int), stream);
  k_bin<<<196, 256, 0, stream>>>(src_i, dst_i, src_j, dst_j, bcnt, bucketbuf);
  k_bktscan<<<1, 256, 0, stream>>>(bcnt, bktbase);
  k_build<<<392, 256, 0, stream>>>(bucketbuf, bcnt, bktbase, csr, cnt2,
                                   row_start2);
  k_tobf16<<<12500, 256, 0, stream>>>(x_i, x_j, xb2);
  k_agg1<<<25000, 256, 0, stream>>>(xb2, csr, row_start2, cnt2, aggb2);
  k_gemm1<<<dim3(784, 2), 256, 0, stream>>>(aggb2, xb2, Wt, b1, h1b2);
  k_agg2<<<2 * BS, 256, 0, stream>>>(h1b2, csr, row_start2, cnt2, ids_i, ids_j,
                                     A2);
  k_head<<<dim3(256, 2), 256, 0, stream>>>(A2, W2hi, W2lo, b2, h2);
  k_out<<<2048, 256, 0, stream>>>(h2, W_out, b_out, out);
}